// Round 6
// baseline (350.488 us; speedup 1.0000x reference)
//
#include <hip/hip_runtime.h>

#define B 16
#define H 32
#define KVH 8
#define HD 128
#define S 4096
#define D 4096
#define NQKV 6144   // 4096 q + 1024 k + 1024 v columns
#define PSPLIT 32   // k-split for QKV projection
#define WSPLIT 32   // k-split for Wo projection
#define NCH 16      // chunks per (b,kvh) panel in flash kernel
#define CROWS (S / NCH)  // 256 rows per chunk
#define NT (CROWS / 32)  // 8 tiles per chunk
#define SCALE 0.08838834764831845f  // 1/sqrt(128)

// ------------------------------------------------- QKV projection (M=16 GEMM)
__global__ void k_proj(const float* __restrict__ hs, const float* __restrict__ Wq,
                       const float* __restrict__ Wk, const float* __restrict__ Wv,
                       float* __restrict__ part) {
  int n = blockIdx.x * 256 + threadIdx.x;
  int k0 = blockIdx.y * (D / PSPLIT);
  const float* w; int ldw, col;
  if (n < 4096)      { w = Wq; ldw = 4096; col = n; }
  else if (n < 5120) { w = Wk; ldw = 1024; col = n - 4096; }
  else               { w = Wv; ldw = 1024; col = n - 5120; }
  float acc[B];
#pragma unroll
  for (int b = 0; b < B; b++) acc[b] = 0.f;
  const float* wp = w + (size_t)k0 * ldw + col;
#pragma unroll 8
  for (int k = 0; k < D / PSPLIT; k++) {
    float wv = wp[(size_t)k * ldw];
#pragma unroll
    for (int b = 0; b < B; b++) acc[b] = fmaf(hs[b * D + k0 + k], wv, acc[b]);
  }
  float* p = part + (size_t)blockIdx.y * (B * NQKV);
#pragma unroll
  for (int b = 0; b < B; b++) p[(size_t)b * NQKV + n] = acc[b];
}

// -------------------------------- reduce partials + RoPE -> qr, new k/v rows
__global__ void k_reduce_rope(const float* __restrict__ part, const float* __restrict__ cosb,
                              const float* __restrict__ sinb, const int* __restrict__ steps,
                              float* __restrict__ qr, float* __restrict__ nkrow,
                              float* __restrict__ nvrow) {
  int i = blockIdx.x * 256 + threadIdx.x;  // < B*NQKV
  int b = i / NQKV, n = i % NQKV;
  float v = 0.f;
#pragma unroll
  for (int c = 0; c < PSPLIT; c++) v += part[(size_t)c * B * NQKV + (size_t)b * NQKV + n];
  if (n < 5120) {
    int d = n & 127;
    int pn = (d < 64) ? n + 64 : n - 64;
    float pv = 0.f;
#pragma unroll
    for (int c = 0; c < PSPLIT; c++) pv += part[(size_t)c * B * NQKV + (size_t)b * NQKV + pn];
    float rot = (d < 64) ? -pv : pv;
    float r = v * cosb[b * HD + d] + rot * sinb[b * HD + d];
    if (n < 4096) qr[(size_t)b * D + n] = r;
    else          nkrow[(size_t)b * KVH * HD + (n - 4096)] = r;
  } else {
    nvrow[(size_t)b * KVH * HD + (n - 5120)] = v;
  }
}

// ---------------- flash: copy K,V (+row sub) + QK^T + online softmax + P*V
// One block per (chunk, kvh, b). Per 32-row tile: K copy+LDS stage -> barrier
// -> per-wave scores + in-register online softmax -> barrier -> V copy +
// rescaled P*V accumulate. K/V register prefetch one tile ahead.
__global__ void __launch_bounds__(256, 4)
k_flash(const float* __restrict__ pastk, const float* __restrict__ pastv,
        const float* __restrict__ nkrow, const float* __restrict__ nvrow,
        const float* __restrict__ qr, const int* __restrict__ steps,
        float* __restrict__ newk, float* __restrict__ newv,
        float* __restrict__ part, float* __restrict__ stats) {
  int ch = blockIdx.x, kvh = blockIdx.y, b = blockIdx.z;
  int t = threadIdx.x;
  __shared__ float4 qs4[128];      // 4 heads x 32 float4
  __shared__ float4 ks4[32 * 32];  // 32 rows x 32 float4, XOR-swizzled
  __shared__ float pbuf[128];      // 4 heads x 32 rows
  __shared__ float alph[4];
  __shared__ float4 red[4][4][32]; // [wave][head][d4]
  int s0 = ch * CROWS;
  int step = steps[b];
  int L = step + 1;
  int h0 = kvh * 4;
  if (t < 128) qs4[t] = ((const float4*)(qr + ((size_t)b * H + h0) * HD))[t];
  int d4 = t & 31, rr = t >> 5;   // staging: rows rr+8j, col d4
  float4 ksub = ((const float4*)(nkrow + (size_t)(b * KVH + kvh) * HD))[d4];
  float4 vsub = ((const float4*)(nvrow + (size_t)(b * KVH + kvh) * HD))[d4];
  const float4* srck = (const float4*)(pastk + ((size_t)(b * KVH + kvh) * S + s0) * HD);
  const float4* srcv = (const float4*)(pastv + ((size_t)(b * KVH + kvh) * S + s0) * HD);
  float4* dstk = (float4*)(newk + ((size_t)(b * KVH + kvh) * S + s0) * HD);
  float4* dstv = (float4*)(newv + ((size_t)(b * KVH + kvh) * S + s0) * HD);
  float m_run = -1e30f, l_run = 0.f;
  float4 acc0 = make_float4(0.f, 0.f, 0.f, 0.f), acc1 = acc0, acc2 = acc0, acc3 = acc0;
  float4 kreg[4], vreg[4], kregN[4], vregN[4];
#pragma unroll
  for (int j = 0; j < 4; ++j) {
    kreg[j] = srck[(rr + 8 * j) * 32 + d4];
    vreg[j] = srcv[(rr + 8 * j) * 32 + d4];
  }
  for (int tile = 0; tile < NT; ++tile) {
    int rbase = s0 + tile * 32;
    bool active = (rbase < L);   // block-uniform
    // ---- K: substitute + store + LDS stage
#pragma unroll
    for (int j = 0; j < 4; ++j) {
      int row = rr + 8 * j;
      if (rbase + row == step) kreg[j] = ksub;
      dstk[tile * 1024 + row * 32 + d4] = kreg[j];
      if (active) ks4[row * 32 + (d4 ^ (row & 7))] = kreg[j];
    }
    if (tile + 1 < NT) {
#pragma unroll
      for (int j = 0; j < 4; ++j)
        kregN[j] = srck[(tile + 1) * 1024 + (rr + 8 * j) * 32 + d4];
    }
    if (active) {
      __syncthreads();
      // ---- scores: wave w = head w; lane&31 = row; halves split the dot
      int row_c = t & 31, half = (t >> 5) & 1, h = t >> 6;
      const float4* qp = &qs4[h * 32 + half * 16];
      const float4* kp = &ks4[row_c * 32];
      int sw = row_c & 7;
      float a0 = 0.f, a1 = 0.f, a2 = 0.f, a3 = 0.f;
#pragma unroll
      for (int r = 0; r < 16; r += 4) {
        float4 k0v = kp[(half * 16 + r)     ^ sw], q0v = qp[r];
        float4 k1v = kp[(half * 16 + r + 1) ^ sw], q1v = qp[r + 1];
        float4 k2v = kp[(half * 16 + r + 2) ^ sw], q2v = qp[r + 2];
        float4 k3v = kp[(half * 16 + r + 3) ^ sw], q3v = qp[r + 3];
        a0 = fmaf(k0v.x, q0v.x, fmaf(k0v.y, q0v.y, fmaf(k0v.z, q0v.z, fmaf(k0v.w, q0v.w, a0))));
        a1 = fmaf(k1v.x, q1v.x, fmaf(k1v.y, q1v.y, fmaf(k1v.z, q1v.z, fmaf(k1v.w, q1v.w, a1))));
        a2 = fmaf(k2v.x, q2v.x, fmaf(k2v.y, q2v.y, fmaf(k2v.z, q2v.z, fmaf(k2v.w, q2v.w, a2))));
        a3 = fmaf(k3v.x, q3v.x, fmaf(k3v.y, q3v.y, fmaf(k3v.z, q3v.z, fmaf(k3v.w, q3v.w, a3))));
      }
      float accv = (a0 + a1) + (a2 + a3);
      accv += __shfl_xor(accv, 32);
      float s = accv * SCALE;
      if (rbase + row_c >= L) s = -1e30f;
      // ---- online softmax (within 32-lane half; halves are duplicates)
      float tmax = s;
#pragma unroll
      for (int o = 1; o < 32; o <<= 1) tmax = fmaxf(tmax, __shfl_xor(tmax, o));
      float mnew = fmaxf(m_run, tmax);
      float p = __expf(s - mnew);
      float psum = p;
#pragma unroll
      for (int o = 1; o < 32; o <<= 1) psum += __shfl_xor(psum, o);
      float alpha = __expf(m_run - mnew);
      l_run = l_run * alpha + psum;
      m_run = mnew;
      pbuf[h * 32 + row_c] = p;
      if ((t & 63) == 0) alph[h] = alpha;
      __syncthreads();
    }
    // ---- V: substitute + store (always), accumulate (active only)
#pragma unroll
    for (int j = 0; j < 4; ++j) {
      int row = rr + 8 * j;
      if (rbase + row == step) vreg[j] = vsub;
      dstv[tile * 1024 + row * 32 + d4] = vreg[j];
    }
    if (tile + 1 < NT) {
#pragma unroll
      for (int j = 0; j < 4; ++j)
        vregN[j] = srcv[(tile + 1) * 1024 + (rr + 8 * j) * 32 + d4];
    }
    if (active) {
      float al0 = alph[0], al1 = alph[1], al2 = alph[2], al3 = alph[3];
      acc0.x *= al0; acc0.y *= al0; acc0.z *= al0; acc0.w *= al0;
      acc1.x *= al1; acc1.y *= al1; acc1.z *= al1; acc1.w *= al1;
      acc2.x *= al2; acc2.y *= al2; acc2.z *= al2; acc2.w *= al2;
      acc3.x *= al3; acc3.y *= al3; acc3.z *= al3; acc3.w *= al3;
#pragma unroll
      for (int j = 0; j < 4; ++j) {
        int row = rr + 8 * j;
        float p0 = pbuf[row], p1 = pbuf[32 + row], p2 = pbuf[64 + row], p3 = pbuf[96 + row];
        float4 v = vreg[j];
        acc0.x = fmaf(p0, v.x, acc0.x); acc0.y = fmaf(p0, v.y, acc0.y);
        acc0.z = fmaf(p0, v.z, acc0.z); acc0.w = fmaf(p0, v.w, acc0.w);
        acc1.x = fmaf(p1, v.x, acc1.x); acc1.y = fmaf(p1, v.y, acc1.y);
        acc1.z = fmaf(p1, v.z, acc1.z); acc1.w = fmaf(p1, v.w, acc1.w);
        acc2.x = fmaf(p2, v.x, acc2.x); acc2.y = fmaf(p2, v.y, acc2.y);
        acc2.z = fmaf(p2, v.z, acc2.z); acc2.w = fmaf(p2, v.w, acc2.w);
        acc3.x = fmaf(p3, v.x, acc3.x); acc3.y = fmaf(p3, v.y, acc3.y);
        acc3.z = fmaf(p3, v.z, acc3.z); acc3.w = fmaf(p3, v.w, acc3.w);
      }
    }
    if (tile + 1 < NT) {
#pragma unroll
      for (int j = 0; j < 4; ++j) { kreg[j] = kregN[j]; vreg[j] = vregN[j]; }
    }
  }
  // ---- block reduction over the 8 rr-groups + stats
  acc0.x += __shfl_xor(acc0.x, 32); acc0.y += __shfl_xor(acc0.y, 32);
  acc0.z += __shfl_xor(acc0.z, 32); acc0.w += __shfl_xor(acc0.w, 32);
  acc1.x += __shfl_xor(acc1.x, 32); acc1.y += __shfl_xor(acc1.y, 32);
  acc1.z += __shfl_xor(acc1.z, 32); acc1.w += __shfl_xor(acc1.w, 32);
  acc2.x += __shfl_xor(acc2.x, 32); acc2.y += __shfl_xor(acc2.y, 32);
  acc2.z += __shfl_xor(acc2.z, 32); acc2.w += __shfl_xor(acc2.w, 32);
  acc3.x += __shfl_xor(acc3.x, 32); acc3.y += __shfl_xor(acc3.y, 32);
  acc3.z += __shfl_xor(acc3.z, 32); acc3.w += __shfl_xor(acc3.w, 32);
  int w = t >> 6;
  if ((t & 32) == 0) {
    red[w][0][d4] = acc0; red[w][1][d4] = acc1;
    red[w][2][d4] = acc2; red[w][3][d4] = acc3;
  }
  __syncthreads();
  if (t < 128) {
    int hh = t >> 5, dd = t & 31;
    float4 x0 = red[0][hh][dd], x1 = red[1][hh][dd], x2 = red[2][hh][dd], x3 = red[3][hh][dd];
    float4 sv;
    sv.x = (x0.x + x1.x) + (x2.x + x3.x);
    sv.y = (x0.y + x1.y) + (x2.y + x3.y);
    sv.z = (x0.z + x1.z) + (x2.z + x3.z);
    sv.w = (x0.w + x1.w) + (x2.w + x3.w);
    ((float4*)(part + (((size_t)ch * B + b) * KVH + kvh) * 512))[t] = sv;
  }
  if ((t & 63) == 0) {
    size_t si = ((((size_t)ch * B + b) * KVH + kvh) * 4 + w) * 2;
    stats[si] = m_run;
    stats[si + 1] = l_run;
  }
}

// ------------- combine split-S partials: ctx = sum(e^{m-M} acc) / sum(e^{m-M} l)
__global__ void k_reduce_ctx(const float* __restrict__ part, const float* __restrict__ stats,
                             float* __restrict__ ctx) {
  int i = blockIdx.x * 256 + threadIdx.x;  // < B*D
  int b = i >> 12, r = i & 4095, h = r >> 7, d = r & 127;
  int kvh = h >> 2, hl = h & 3;
  float M = -1e30f;
#pragma unroll
  for (int c = 0; c < NCH; c++)
    M = fmaxf(M, stats[((((size_t)c * B + b) * KVH + kvh) * 4 + hl) * 2]);
  float num = 0.f, den = 0.f;
#pragma unroll
  for (int c = 0; c < NCH; c++) {
    size_t si = ((((size_t)c * B + b) * KVH + kvh) * 4 + hl) * 2;
    float wgt = __expf(stats[si] - M);
    den += wgt * stats[si + 1];
    num += wgt * part[(((size_t)c * B + b) * KVH + kvh) * 512 + hl * 128 + d];
  }
  ctx[i] = num / den;
}

// ----------------------------------------------- output projection (M=16)
__global__ void k_wo(const float* __restrict__ ctx, const float* __restrict__ Wo,
                     float* __restrict__ part) {
  int n = blockIdx.x * 256 + threadIdx.x;  // < 4096
  int k0 = blockIdx.y * (D / WSPLIT);
  float acc[B];
#pragma unroll
  for (int b = 0; b < B; b++) acc[b] = 0.f;
  const float* wp = Wo + (size_t)k0 * D + n;
#pragma unroll 8
  for (int k = 0; k < D / WSPLIT; k++) {
    float wv = wp[(size_t)k * D];
#pragma unroll
    for (int b = 0; b < B; b++) acc[b] = fmaf(ctx[b * D + k0 + k], wv, acc[b]);
  }
  float* p = part + (size_t)blockIdx.y * (B * D);
#pragma unroll
  for (int b = 0; b < B; b++) p[(size_t)b * D + n] = acc[b];
}

__global__ void k_reduce_out(const float* __restrict__ part, float* __restrict__ out) {
  int i = blockIdx.x * 256 + threadIdx.x;  // < B*D
  float s = 0.f;
#pragma unroll
  for (int c = 0; c < WSPLIT; c++) s += part[(size_t)c * B * D + i];
  out[i] = s;
}

// ----------------------------------------------------------------- launch
extern "C" void kernel_launch(void* const* d_in, const int* in_sizes, int n_in,
                              void* d_out, int out_size, void* d_ws, size_t ws_size,
                              hipStream_t stream) {
  const float* hs    = (const float*)d_in[0];
  const int*   steps = (const int*)d_in[2];
  const float* cosb  = (const float*)d_in[3];
  const float* sinb  = (const float*)d_in[4];
  const float* pk    = (const float*)d_in[5];
  const float* pvv   = (const float*)d_in[6];
  const float* Wq    = (const float*)d_in[7];
  const float* Wk    = (const float*)d_in[8];
  const float* Wv    = (const float*)d_in[9];
  const float* Wo    = (const float*)d_in[10];

  float* attn_out = (float*)d_out;
  float* newk = attn_out + (size_t)B * D;
  float* newv = newk + (size_t)B * KVH * S * HD;

  float* ws = (float*)d_ws;
  // Region A (disjoint lifetimes): proj partials (3.1M) -> Wo partials (2.1M)
  float* A        = ws;                               // 3,145,728 floats
  float* p_part   = A;
  float* p_wopart = A;
  float* p_pvpart = A + 3145728;                      // 1,048,576
  float* p_stats  = p_pvpart + 1048576;               //    16,384
  float* p_qr     = p_stats + 16384;                  //    65,536
  float* p_nkrow  = p_qr + (size_t)B * D;             //    16,384
  float* p_nvrow  = p_nkrow + (size_t)B * KVH * HD;   //    16,384
  float* p_ctx    = p_nvrow + (size_t)B * KVH * HD;   //    65,536

  hipLaunchKernelGGL(k_proj, dim3(NQKV / 256, PSPLIT), dim3(256), 0, stream,
                     hs, Wq, Wk, Wv, p_part);
  hipLaunchKernelGGL(k_reduce_rope, dim3(B * NQKV / 256), dim3(256), 0, stream,
                     p_part, cosb, sinb, steps, p_qr, p_nkrow, p_nvrow);
  hipLaunchKernelGGL(k_flash, dim3(NCH, KVH, B), dim3(256), 0, stream,
                     pk, pvv, p_nkrow, p_nvrow, p_qr, steps, newk, newv,
                     p_pvpart, p_stats);
  hipLaunchKernelGGL(k_reduce_ctx, dim3(B * D / 256), dim3(256), 0, stream,
                     p_pvpart, p_stats, p_ctx);
  hipLaunchKernelGGL(k_wo, dim3(D / 256, WSPLIT), dim3(256), 0, stream,
                     p_ctx, Wo, p_wopart);
  hipLaunchKernelGGL(k_reduce_out, dim3(B * D / 256), dim3(256), 0, stream,
                     p_wopart, attn_out);
}

// Round 7
// 343.435 us; speedup vs baseline: 1.0205x; 1.0205x over previous
//
#include <hip/hip_runtime.h>

#define B 16
#define H 32
#define KVH 8
#define HD 128
#define S 4096
#define D 4096
#define NQKV 6144   // 4096 q + 1024 k + 1024 v columns
#define PSPLIT 32   // k-split for QKV projection
#define WSPLIT 32   // k-split for Wo projection
#define NCH 16      // chunks per (b,kvh) panel in fused copy kernels
#define CROWS (S / NCH)  // 256 rows per chunk
#define SCALE 0.08838834764831845f  // 1/sqrt(128)

// ------------------------------------------------- QKV projection (M=16 GEMM)
__global__ void k_proj(const float* __restrict__ hs, const float* __restrict__ Wq,
                       const float* __restrict__ Wk, const float* __restrict__ Wv,
                       float* __restrict__ part) {
  int n = blockIdx.x * 256 + threadIdx.x;
  int k0 = blockIdx.y * (D / PSPLIT);
  const float* w; int ldw, col;
  if (n < 4096)      { w = Wq; ldw = 4096; col = n; }
  else if (n < 5120) { w = Wk; ldw = 1024; col = n - 4096; }
  else               { w = Wv; ldw = 1024; col = n - 5120; }
  float acc[B];
#pragma unroll
  for (int b = 0; b < B; b++) acc[b] = 0.f;
  const float* wp = w + (size_t)k0 * ldw + col;
#pragma unroll 8
  for (int k = 0; k < D / PSPLIT; k++) {
    float wv = wp[(size_t)k * ldw];
#pragma unroll
    for (int b = 0; b < B; b++) acc[b] = fmaf(hs[b * D + k0 + k], wv, acc[b]);
  }
  float* p = part + (size_t)blockIdx.y * (B * NQKV);
#pragma unroll
  for (int b = 0; b < B; b++) p[(size_t)b * NQKV + n] = acc[b];
}

// -------------------------------- reduce partials + RoPE -> qr, new k/v rows
__global__ void k_reduce_rope(const float* __restrict__ part, const float* __restrict__ cosb,
                              const float* __restrict__ sinb, const int* __restrict__ steps,
                              float* __restrict__ qr, float* __restrict__ nkrow,
                              float* __restrict__ nvrow) {
  int i = blockIdx.x * 256 + threadIdx.x;  // < B*NQKV
  int b = i / NQKV, n = i % NQKV;
  float v = 0.f;
#pragma unroll
  for (int c = 0; c < PSPLIT; c++) v += part[(size_t)c * B * NQKV + (size_t)b * NQKV + n];
  if (n < 5120) {
    int d = n & 127;
    int pn = (d < 64) ? n + 64 : n - 64;
    float pv = 0.f;
#pragma unroll
    for (int c = 0; c < PSPLIT; c++) pv += part[(size_t)c * B * NQKV + (size_t)b * NQKV + pn];
    float rot = (d < 64) ? -pv : pv;
    float r = v * cosb[b * HD + d] + rot * sinb[b * HD + d];
    if (n < 4096) qr[(size_t)b * D + n] = r;
    else          nkrow[(size_t)b * KVH * HD + (n - 4096)] = r;
  } else {
    nvrow[(size_t)b * KVH * HD + (n - 5120)] = v;
  }
}

// -------------------- fused: copy past_key -> new_key (+row sub) + QK scores
// Barrier-free, LDS-free. 16-lane group owns a row; lane ln holds float4
// slots {ln, ln+16}. Q sliced into 32 VGPR/lane. Row dot completes with
// DPP-able __shfl_xor {1,2,4,8} within the 16-lane group.
__global__ void k_fusedK(const float* __restrict__ pastk, const float* __restrict__ nkrow,
                         const float* __restrict__ qr, const int* __restrict__ steps,
                         float* __restrict__ newk, float* __restrict__ scores) {
  int ch = blockIdx.x, kvh = blockIdx.y, b = blockIdx.z;
  int t = threadIdx.x;
  int ln = t & 15, rg = t >> 4;  // 16 rows in flight per pass
  int s0 = ch * CROWS;
  int step = steps[b];
  int L = step + 1;
  int h0 = kvh * 4;
  const float4* qbase = (const float4*)(qr + ((size_t)b * H + h0) * HD);
  float4 q0[4], q1[4];
#pragma unroll
  for (int h = 0; h < 4; h++) {
    q0[h] = qbase[h * 32 + ln];
    q1[h] = qbase[h * 32 + ln + 16];
  }
  const float4* subp = (const float4*)(nkrow + (size_t)(b * KVH + kvh) * HD);
  float4 sub0 = subp[ln], sub1 = subp[ln + 16];
  const float4* src = (const float4*)(pastk + ((size_t)(b * KVH + kvh) * S + s0) * HD);
  float4*       dst = (float4*)(newk + ((size_t)(b * KVH + kvh) * S + s0) * HD);
  float* srow = scores + (size_t)(b * H + h0) * S + s0;
#pragma unroll 4
  for (int it = 0; it < CROWS / 16; ++it) {
    int row = it * 16 + rg;
    size_t o0 = (size_t)row * 32 + ln;
    float4 k0 = src[o0];
    float4 k1 = src[o0 + 16];
    if (s0 + row == step) { k0 = sub0; k1 = sub1; }
    dst[o0] = k0;
    dst[o0 + 16] = k1;
    if (s0 + row < L) {
      float a0, a1, a2, a3;
      a0 = fmaf(k0.x, q0[0].x, fmaf(k0.y, q0[0].y, fmaf(k0.z, q0[0].z, fmaf(k0.w, q0[0].w,
           fmaf(k1.x, q1[0].x, fmaf(k1.y, q1[0].y, fmaf(k1.z, q1[0].z, k1.w * q1[0].w)))))));
      a1 = fmaf(k0.x, q0[1].x, fmaf(k0.y, q0[1].y, fmaf(k0.z, q0[1].z, fmaf(k0.w, q0[1].w,
           fmaf(k1.x, q1[1].x, fmaf(k1.y, q1[1].y, fmaf(k1.z, q1[1].z, k1.w * q1[1].w)))))));
      a2 = fmaf(k0.x, q0[2].x, fmaf(k0.y, q0[2].y, fmaf(k0.z, q0[2].z, fmaf(k0.w, q0[2].w,
           fmaf(k1.x, q1[2].x, fmaf(k1.y, q1[2].y, fmaf(k1.z, q1[2].z, k1.w * q1[2].w)))))));
      a3 = fmaf(k0.x, q0[3].x, fmaf(k0.y, q0[3].y, fmaf(k0.z, q0[3].z, fmaf(k0.w, q0[3].w,
           fmaf(k1.x, q1[3].x, fmaf(k1.y, q1[3].y, fmaf(k1.z, q1[3].z, k1.w * q1[3].w)))))));
#pragma unroll
      for (int o = 1; o < 16; o <<= 1) {
        a0 += __shfl_xor(a0, o);
        a1 += __shfl_xor(a1, o);
        a2 += __shfl_xor(a2, o);
        a3 += __shfl_xor(a3, o);
      }
      if (ln < 4) {
        float my = (ln == 0) ? a0 : (ln == 1) ? a1 : (ln == 2) ? a2 : a3;
        srow[(size_t)ln * S + row] = my * SCALE;
      }
    }
  }
}

// --------------- softmax: in-place normalize scores -> probs (per b,h)
__global__ void k_smax(float* __restrict__ scores, const int* __restrict__ steps) {
  int bid = blockIdx.x;
  int b = bid >> 5, h = bid & 31;
  int t = threadIdx.x;
  __shared__ float red[4];
  int L = steps[b] + 1;
  float* srow = scores + (size_t)(b * H + h) * S;
  float lmax = -1e30f;
  for (int s = t; s < L; s += 256) lmax = fmaxf(lmax, srow[s]);
#pragma unroll
  for (int o = 32; o > 0; o >>= 1) lmax = fmaxf(lmax, __shfl_xor(lmax, o));
  if ((t & 63) == 0) red[t >> 6] = lmax;
  __syncthreads();
  float gm = fmaxf(fmaxf(red[0], red[1]), fmaxf(red[2], red[3]));
  float lsum = 0.f;
  for (int s = t; s < L; s += 256) {
    float p = __expf(srow[s] - gm);
    srow[s] = p;
    lsum += p;
  }
#pragma unroll
  for (int o = 32; o > 0; o >>= 1) lsum += __shfl_xor(lsum, o);
  __syncthreads();
  if ((t & 63) == 0) red[t >> 6] = lsum;
  __syncthreads();
  float inv = 1.f / (red[0] + red[1] + red[2] + red[3]);
  for (int s = t; s < L; s += 256) srow[s] *= inv;
}

// --------------- fused: copy past_value -> new_value (+row sub) + P·V
// Barrier-free stream: lane owns (d4, row-slice); probs are pre-normalized,
// read as row-uniform broadcast loads. Single LDS reduce at block end.
__global__ void k_fusedV(const float* __restrict__ pastv, const float* __restrict__ nvrow,
                         const float* __restrict__ probs, const int* __restrict__ steps,
                         float* __restrict__ newv, float* __restrict__ part) {
  int ch = blockIdx.x, kvh = blockIdx.y, b = blockIdx.z;
  int t = threadIdx.x;
  int d4 = t & 31, rr = t >> 5;  // rr in 0..7
  int s0 = ch * CROWS;
  int step = steps[b];
  int L = step + 1;
  int h0 = kvh * 4;
  float4 subv = ((const float4*)(nvrow + (size_t)(b * KVH + kvh) * HD))[d4];
  const float4* src = (const float4*)(pastv + ((size_t)(b * KVH + kvh) * S + s0) * HD);
  float4*       dst = (float4*)(newv + ((size_t)(b * KVH + kvh) * S + s0) * HD);
  const float* pb = probs + (size_t)(b * H + h0) * S + s0;
  float4 a0 = make_float4(0.f, 0.f, 0.f, 0.f), a1 = a0, a2 = a0, a3 = a0;
#pragma unroll 4
  for (int i = 0; i < CROWS / 8; ++i) {
    int r = i * 8 + rr;
    float4 v = src[r * 32 + d4];
    if (s0 + r == step) v = subv;
    dst[r * 32 + d4] = v;
    if (s0 + r < L) {
      float q0 = pb[r], q1 = pb[S + r], q2 = pb[2 * S + r], q3 = pb[3 * S + r];
      a0.x = fmaf(q0, v.x, a0.x); a0.y = fmaf(q0, v.y, a0.y);
      a0.z = fmaf(q0, v.z, a0.z); a0.w = fmaf(q0, v.w, a0.w);
      a1.x = fmaf(q1, v.x, a1.x); a1.y = fmaf(q1, v.y, a1.y);
      a1.z = fmaf(q1, v.z, a1.z); a1.w = fmaf(q1, v.w, a1.w);
      a2.x = fmaf(q2, v.x, a2.x); a2.y = fmaf(q2, v.y, a2.y);
      a2.z = fmaf(q2, v.z, a2.z); a2.w = fmaf(q2, v.w, a2.w);
      a3.x = fmaf(q3, v.x, a3.x); a3.y = fmaf(q3, v.y, a3.y);
      a3.z = fmaf(q3, v.z, a3.z); a3.w = fmaf(q3, v.w, a3.w);
    }
  }
  // combine rr pairs within wave (t^32 flips rr bit 0)
  a0.x += __shfl_xor(a0.x, 32); a0.y += __shfl_xor(a0.y, 32);
  a0.z += __shfl_xor(a0.z, 32); a0.w += __shfl_xor(a0.w, 32);
  a1.x += __shfl_xor(a1.x, 32); a1.y += __shfl_xor(a1.y, 32);
  a1.z += __shfl_xor(a1.z, 32); a1.w += __shfl_xor(a1.w, 32);
  a2.x += __shfl_xor(a2.x, 32); a2.y += __shfl_xor(a2.y, 32);
  a2.z += __shfl_xor(a2.z, 32); a2.w += __shfl_xor(a2.w, 32);
  a3.x += __shfl_xor(a3.x, 32); a3.y += __shfl_xor(a3.y, 32);
  a3.z += __shfl_xor(a3.z, 32); a3.w += __shfl_xor(a3.w, 32);
  __shared__ float4 red[4][4][32];  // [wave][head][d4]
  int w = t >> 6;
  if ((t & 32) == 0) {
    red[w][0][d4] = a0; red[w][1][d4] = a1; red[w][2][d4] = a2; red[w][3][d4] = a3;
  }
  __syncthreads();
  if (t < 128) {
    int hh = t >> 5, dd = t & 31;
    float4 x0 = red[0][hh][dd], x1 = red[1][hh][dd], x2 = red[2][hh][dd], x3 = red[3][hh][dd];
    float4 s;
    s.x = (x0.x + x1.x) + (x2.x + x3.x);
    s.y = (x0.y + x1.y) + (x2.y + x3.y);
    s.z = (x0.z + x1.z) + (x2.z + x3.z);
    s.w = (x0.w + x1.w) + (x2.w + x3.w);
    ((float4*)(part + (((size_t)ch * B + b) * KVH + kvh) * 512))[t] = s;
  }
}

__global__ void k_reduce_ctx(const float* __restrict__ part, float* __restrict__ ctx) {
  int i = blockIdx.x * 256 + threadIdx.x;  // < B*D
  int b = i >> 12, r = i & 4095, h = r >> 7, d = r & 127;
  int kvh = h >> 2, hl = h & 3;
  float s = 0.f;
#pragma unroll
  for (int c = 0; c < NCH; c++)
    s += part[(((size_t)c * B + b) * KVH + kvh) * 512 + hl * 128 + d];
  ctx[i] = s;
}

// ----------------------------------------------- output projection (M=16)
__global__ void k_wo(const float* __restrict__ ctx, const float* __restrict__ Wo,
                     float* __restrict__ part) {
  int n = blockIdx.x * 256 + threadIdx.x;  // < 4096
  int k0 = blockIdx.y * (D / WSPLIT);
  float acc[B];
#pragma unroll
  for (int b = 0; b < B; b++) acc[b] = 0.f;
  const float* wp = Wo + (size_t)k0 * D + n;
#pragma unroll 8
  for (int k = 0; k < D / WSPLIT; k++) {
    float wv = wp[(size_t)k * D];
#pragma unroll
    for (int b = 0; b < B; b++) acc[b] = fmaf(ctx[b * D + k0 + k], wv, acc[b]);
  }
  float* p = part + (size_t)blockIdx.y * (B * D);
#pragma unroll
  for (int b = 0; b < B; b++) p[(size_t)b * D + n] = acc[b];
}

__global__ void k_reduce_out(const float* __restrict__ part, float* __restrict__ out) {
  int i = blockIdx.x * 256 + threadIdx.x;  // < B*D
  float s = 0.f;
#pragma unroll
  for (int c = 0; c < WSPLIT; c++) s += part[(size_t)c * B * D + i];
  out[i] = s;
}

// ----------------------------------------------------------------- launch
extern "C" void kernel_launch(void* const* d_in, const int* in_sizes, int n_in,
                              void* d_out, int out_size, void* d_ws, size_t ws_size,
                              hipStream_t stream) {
  const float* hs    = (const float*)d_in[0];
  const int*   steps = (const int*)d_in[2];
  const float* cosb  = (const float*)d_in[3];
  const float* sinb  = (const float*)d_in[4];
  const float* pk    = (const float*)d_in[5];
  const float* pvv   = (const float*)d_in[6];
  const float* Wq    = (const float*)d_in[7];
  const float* Wk    = (const float*)d_in[8];
  const float* Wv    = (const float*)d_in[9];
  const float* Wo    = (const float*)d_in[10];

  float* attn_out = (float*)d_out;
  float* newk = attn_out + (size_t)B * D;
  float* newv = newk + (size_t)B * KVH * S * HD;

  float* ws = (float*)d_ws;
  // Region A (lifetimes disjoint): proj partials (3.1M) -> scores/probs (2.1M)
  //                                -> Wo partials (2.1M)
  float* A        = ws;                               // 3,145,728 floats
  float* p_part   = A;
  float* p_scores = A;
  float* p_wopart = A;
  float* p_pvpart = A + 3145728;                      // 1,048,576
  float* p_qr     = p_pvpart + 1048576;               //    65,536
  float* p_nkrow  = p_qr + (size_t)B * D;             //    16,384
  float* p_nvrow  = p_nkrow + (size_t)B * KVH * HD;   //    16,384
  float* p_ctx    = p_nvrow + (size_t)B * KVH * HD;   //    65,536

  hipLaunchKernelGGL(k_proj, dim3(NQKV / 256, PSPLIT), dim3(256), 0, stream,
                     hs, Wq, Wk, Wv, p_part);
  hipLaunchKernelGGL(k_reduce_rope, dim3(B * NQKV / 256), dim3(256), 0, stream,
                     p_part, cosb, sinb, steps, p_qr, p_nkrow, p_nvrow);
  hipLaunchKernelGGL(k_fusedK, dim3(NCH, KVH, B), dim3(256), 0, stream,
                     pk, p_nkrow, p_qr, steps, newk, p_scores);
  hipLaunchKernelGGL(k_smax, dim3(B * H), dim3(256), 0, stream,
                     p_scores, steps);
  hipLaunchKernelGGL(k_fusedV, dim3(NCH, KVH, B), dim3(256), 0, stream,
                     pvv, p_nvrow, p_scores, steps, newv, p_pvpart);
  hipLaunchKernelGGL(k_reduce_ctx, dim3(B * D / 256), dim3(256), 0, stream,
                     p_pvpart, p_ctx);
  hipLaunchKernelGGL(k_wo, dim3(D / 256, WSPLIT), dim3(256), 0, stream,
                     p_ctx, Wo, p_wopart);
  hipLaunchKernelGGL(k_reduce_out, dim3(B * D / 256), dim3(256), 0, stream,
                     p_wopart, attn_out);
}

// Round 9
// 316.947 us; speedup vs baseline: 1.1058x; 1.0836x over previous
//
#include <hip/hip_runtime.h>

#define B 16
#define H 32
#define KVH 8
#define HD 128
#define S 4096
#define D 4096
#define NQKV 6144   // 4096 q + 1024 k + 1024 v columns
#define PSPLIT 32   // k-split for QKV projection
#define WSPLIT 32   // k-split for Wo projection
#define NCH 16      // chunks per (b,kvh) panel in fused copy kernels
#define CROWS (S / NCH)  // 256 rows per chunk
#define SCALE 0.08838834764831845f  // 1/sqrt(128)

typedef float nfloat4 __attribute__((ext_vector_type(4)));

__device__ __forceinline__ float4 ntload4(const float4* p) {
  nfloat4 r = __builtin_nontemporal_load(reinterpret_cast<const nfloat4*>(p));
  return *reinterpret_cast<float4*>(&r);
}
__device__ __forceinline__ void ntstore4(float4* p, float4 v) {
  __builtin_nontemporal_store(*reinterpret_cast<nfloat4*>(&v),
                              reinterpret_cast<nfloat4*>(p));
}

// ------------------------------------------------- QKV projection (M=16 GEMM)
__global__ void k_proj(const float* __restrict__ hs, const float* __restrict__ Wq,
                       const float* __restrict__ Wk, const float* __restrict__ Wv,
                       float* __restrict__ part) {
  int n = blockIdx.x * 256 + threadIdx.x;
  int k0 = blockIdx.y * (D / PSPLIT);
  const float* w; int ldw, col;
  if (n < 4096)      { w = Wq; ldw = 4096; col = n; }
  else if (n < 5120) { w = Wk; ldw = 1024; col = n - 4096; }
  else               { w = Wv; ldw = 1024; col = n - 5120; }
  float acc[B];
#pragma unroll
  for (int b = 0; b < B; b++) acc[b] = 0.f;
  const float* wp = w + (size_t)k0 * ldw + col;
#pragma unroll 8
  for (int k = 0; k < D / PSPLIT; k++) {
    float wv = wp[(size_t)k * ldw];
#pragma unroll
    for (int b = 0; b < B; b++) acc[b] = fmaf(hs[b * D + k0 + k], wv, acc[b]);
  }
  float* p = part + (size_t)blockIdx.y * (B * NQKV);
#pragma unroll
  for (int b = 0; b < B; b++) p[(size_t)b * NQKV + n] = acc[b];
}

// -------------------------------- reduce partials + RoPE -> qr, new k/v rows
__global__ void k_reduce_rope(const float* __restrict__ part, const float* __restrict__ cosb,
                              const float* __restrict__ sinb, const int* __restrict__ steps,
                              float* __restrict__ qr, float* __restrict__ nkrow,
                              float* __restrict__ nvrow) {
  int i = blockIdx.x * 256 + threadIdx.x;  // < B*NQKV
  int b = i / NQKV, n = i % NQKV;
  float v = 0.f;
#pragma unroll
  for (int c = 0; c < PSPLIT; c++) v += part[(size_t)c * B * NQKV + (size_t)b * NQKV + n];
  if (n < 5120) {
    int d = n & 127;
    int pn = (d < 64) ? n + 64 : n - 64;
    float pv = 0.f;
#pragma unroll
    for (int c = 0; c < PSPLIT; c++) pv += part[(size_t)c * B * NQKV + (size_t)b * NQKV + pn];
    float rot = (d < 64) ? -pv : pv;
    float r = v * cosb[b * HD + d] + rot * sinb[b * HD + d];
    if (n < 4096) qr[(size_t)b * D + n] = r;
    else          nkrow[(size_t)b * KVH * HD + (n - 4096)] = r;
  } else {
    nvrow[(size_t)b * KVH * HD + (n - 5120)] = v;
  }
}

// -------------------- fused: copy past_key -> new_key (+row sub) + QK scores
// Barrier-free stream (NT load/store). 16-lane group owns a row; lane ln holds
// float4 slots {ln, ln+16}. Scores buffered in LDS, dumped coalesced at end.
__global__ void k_fusedK(const float* __restrict__ pastk, const float* __restrict__ nkrow,
                         const float* __restrict__ qr, const int* __restrict__ steps,
                         float* __restrict__ newk, float* __restrict__ scores) {
  int ch = blockIdx.x, kvh = blockIdx.y, b = blockIdx.z;
  int t = threadIdx.x;
  int ln = t & 15, rg = t >> 4;  // 16 rows in flight per pass
  __shared__ float sbuf[CROWS][4];  // [row][head], conflict-free writes
  int s0 = ch * CROWS;
  int step = steps[b];
  int L = step + 1;
  int h0 = kvh * 4;
  const float4* qbase = (const float4*)(qr + ((size_t)b * H + h0) * HD);
  float4 q0[4], q1[4];
#pragma unroll
  for (int h = 0; h < 4; h++) {
    q0[h] = qbase[h * 32 + ln];
    q1[h] = qbase[h * 32 + ln + 16];
  }
  const float4* subp = (const float4*)(nkrow + (size_t)(b * KVH + kvh) * HD);
  float4 sub0 = subp[ln], sub1 = subp[ln + 16];
  const float4* src = (const float4*)(pastk + ((size_t)(b * KVH + kvh) * S + s0) * HD);
  float4*       dst = (float4*)(newk + ((size_t)(b * KVH + kvh) * S + s0) * HD);
#pragma unroll 4
  for (int it = 0; it < CROWS / 16; ++it) {
    int row = it * 16 + rg;
    size_t o0 = (size_t)row * 32 + ln;
    float4 k0 = ntload4(&src[o0]);
    float4 k1 = ntload4(&src[o0 + 16]);
    if (s0 + row == step) { k0 = sub0; k1 = sub1; }
    ntstore4(&dst[o0], k0);
    ntstore4(&dst[o0 + 16], k1);
    if (s0 + it * 16 < L) {  // wave-uniform skip of dead 16-row groups
      float a0, a1, a2, a3;
      a0 = fmaf(k0.x, q0[0].x, fmaf(k0.y, q0[0].y, fmaf(k0.z, q0[0].z, fmaf(k0.w, q0[0].w,
           fmaf(k1.x, q1[0].x, fmaf(k1.y, q1[0].y, fmaf(k1.z, q1[0].z, k1.w * q1[0].w)))))));
      a1 = fmaf(k0.x, q0[1].x, fmaf(k0.y, q0[1].y, fmaf(k0.z, q0[1].z, fmaf(k0.w, q0[1].w,
           fmaf(k1.x, q1[1].x, fmaf(k1.y, q1[1].y, fmaf(k1.z, q1[1].z, k1.w * q1[1].w)))))));
      a2 = fmaf(k0.x, q0[2].x, fmaf(k0.y, q0[2].y, fmaf(k0.z, q0[2].z, fmaf(k0.w, q0[2].w,
           fmaf(k1.x, q1[2].x, fmaf(k1.y, q1[2].y, fmaf(k1.z, q1[2].z, k1.w * q1[2].w)))))));
      a3 = fmaf(k0.x, q0[3].x, fmaf(k0.y, q0[3].y, fmaf(k0.z, q0[3].z, fmaf(k0.w, q0[3].w,
           fmaf(k1.x, q1[3].x, fmaf(k1.y, q1[3].y, fmaf(k1.z, q1[3].z, k1.w * q1[3].w)))))));
#pragma unroll
      for (int o = 1; o < 16; o <<= 1) {
        a0 += __shfl_xor(a0, o);
        a1 += __shfl_xor(a1, o);
        a2 += __shfl_xor(a2, o);
        a3 += __shfl_xor(a3, o);
      }
      if (ln < 4) {
        float my = (ln == 0) ? a0 : (ln == 1) ? a1 : (ln == 2) ? a2 : a3;
        sbuf[row][ln] = my * SCALE;
      }
    }
  }
  if (s0 < L) {  // dump scores coalesced (rows >= L contain junk, never read)
    __syncthreads();
    float* srow = scores + (size_t)(b * H + h0) * S + s0;
#pragma unroll
    for (int j = 0; j < 4; ++j) srow[(size_t)j * S + t] = sbuf[t][j];
  }
}

// --------------- softmax: in-place normalize scores -> probs (per b,h)
__global__ void k_smax(float* __restrict__ scores, const int* __restrict__ steps) {
  int bid = blockIdx.x;
  int b = bid >> 5, h = bid & 31;
  int t = threadIdx.x;
  __shared__ float red[4];
  int L = steps[b] + 1;
  float* srow = scores + (size_t)(b * H + h) * S;
  float lmax = -1e30f;
  for (int s = t; s < L; s += 256) lmax = fmaxf(lmax, srow[s]);
#pragma unroll
  for (int o = 32; o > 0; o >>= 1) lmax = fmaxf(lmax, __shfl_xor(lmax, o));
  if ((t & 63) == 0) red[t >> 6] = lmax;
  __syncthreads();
  float gm = fmaxf(fmaxf(red[0], red[1]), fmaxf(red[2], red[3]));
  float lsum = 0.f;
  for (int s = t; s < L; s += 256) {
    float p = __expf(srow[s] - gm);
    srow[s] = p;
    lsum += p;
  }
#pragma unroll
  for (int o = 32; o > 0; o >>= 1) lsum += __shfl_xor(lsum, o);
  __syncthreads();
  if ((t & 63) == 0) red[t >> 6] = lsum;
  __syncthreads();
  float inv = 1.f / (red[0] + red[1] + red[2] + red[3]);
  for (int s = t; s < L; s += 256) srow[s] *= inv;
}

// --------------- fused: copy past_value -> new_value (+row sub) + P·V
// NT stream; probs staged once into LDS (zero-padded past L) so the PV loop
// is unguarded broadcast ds_reads. Single staging barrier + one final reduce.
__global__ void k_fusedV(const float* __restrict__ pastv, const float* __restrict__ nvrow,
                         const float* __restrict__ probs, const int* __restrict__ steps,
                         float* __restrict__ newv, float* __restrict__ part) {
  int ch = blockIdx.x, kvh = blockIdx.y, b = blockIdx.z;
  int t = threadIdx.x;
  int d4 = t & 31, rr = t >> 5;  // rr in 0..7
  __shared__ float pbuf[CROWS][4];  // [row][head]
  int s0 = ch * CROWS;
  int step = steps[b];
  int L = step + 1;
  int h0 = kvh * 4;
  bool any = (s0 < L);  // block-uniform
  float4 subv = ((const float4*)(nvrow + (size_t)(b * KVH + kvh) * HD))[d4];
  const float4* src = (const float4*)(pastv + ((size_t)(b * KVH + kvh) * S + s0) * HD);
  float4*       dst = (float4*)(newv + ((size_t)(b * KVH + kvh) * S + s0) * HD);
  if (any) {
    const float* pb = probs + (size_t)(b * H + h0) * S + s0;
#pragma unroll
    for (int j = 0; j < 4; ++j)
      pbuf[t][j] = (s0 + t < L) ? pb[(size_t)j * S + t] : 0.f;
    __syncthreads();
  }
  float4 a0 = make_float4(0.f, 0.f, 0.f, 0.f), a1 = a0, a2 = a0, a3 = a0;
#pragma unroll 4
  for (int i = 0; i < CROWS / 8; ++i) {
    int r = i * 8 + rr;
    float4 v = ntload4(&src[r * 32 + d4]);
    if (s0 + r == step) v = subv;
    ntstore4(&dst[r * 32 + d4], v);
    if (any && i * 8 < L - s0) {  // wave-uniform; probs zero-padded
      float q0 = pbuf[r][0], q1 = pbuf[r][1], q2 = pbuf[r][2], q3 = pbuf[r][3];
      a0.x = fmaf(q0, v.x, a0.x); a0.y = fmaf(q0, v.y, a0.y);
      a0.z = fmaf(q0, v.z, a0.z); a0.w = fmaf(q0, v.w, a0.w);
      a1.x = fmaf(q1, v.x, a1.x); a1.y = fmaf(q1, v.y, a1.y);
      a1.z = fmaf(q1, v.z, a1.z); a1.w = fmaf(q1, v.w, a1.w);
      a2.x = fmaf(q2, v.x, a2.x); a2.y = fmaf(q2, v.y, a2.y);
      a2.z = fmaf(q2, v.z, a2.z); a2.w = fmaf(q2, v.w, a2.w);
      a3.x = fmaf(q3, v.x, a3.x); a3.y = fmaf(q3, v.y, a3.y);
      a3.z = fmaf(q3, v.z, a3.z); a3.w = fmaf(q3, v.w, a3.w);
    }
  }
  // combine rr pairs within wave (t^32 flips rr bit 0)
  a0.x += __shfl_xor(a0.x, 32); a0.y += __shfl_xor(a0.y, 32);
  a0.z += __shfl_xor(a0.z, 32); a0.w += __shfl_xor(a0.w, 32);
  a1.x += __shfl_xor(a1.x, 32); a1.y += __shfl_xor(a1.y, 32);
  a1.z += __shfl_xor(a1.z, 32); a1.w += __shfl_xor(a1.w, 32);
  a2.x += __shfl_xor(a2.x, 32); a2.y += __shfl_xor(a2.y, 32);
  a2.z += __shfl_xor(a2.z, 32); a2.w += __shfl_xor(a2.w, 32);
  a3.x += __shfl_xor(a3.x, 32); a3.y += __shfl_xor(a3.y, 32);
  a3.z += __shfl_xor(a3.z, 32); a3.w += __shfl_xor(a3.w, 32);
  __shared__ float4 red[4][4][32];  // [wave][head][d4]
  int w = t >> 6;
  __syncthreads();  // all pbuf reads complete before any wave proceeds
  if ((t & 32) == 0) {
    red[w][0][d4] = a0; red[w][1][d4] = a1; red[w][2][d4] = a2; red[w][3][d4] = a3;
  }
  __syncthreads();
  if (t < 128) {
    int hh = t >> 5, dd = t & 31;
    float4 x0 = red[0][hh][dd], x1 = red[1][hh][dd], x2 = red[2][hh][dd], x3 = red[3][hh][dd];
    float4 s;
    s.x = (x0.x + x1.x) + (x2.x + x3.x);
    s.y = (x0.y + x1.y) + (x2.y + x3.y);
    s.z = (x0.z + x1.z) + (x2.z + x3.z);
    s.w = (x0.w + x1.w) + (x2.w + x3.w);
    ((float4*)(part + (((size_t)ch * B + b) * KVH + kvh) * 512))[t] = s;
  }
}

__global__ void k_reduce_ctx(const float* __restrict__ part, float* __restrict__ ctx) {
  int i = blockIdx.x * 256 + threadIdx.x;  // < B*D
  int b = i >> 12, r = i & 4095, h = r >> 7, d = r & 127;
  int kvh = h >> 2, hl = h & 3;
  float s = 0.f;
#pragma unroll
  for (int c = 0; c < NCH; c++)
    s += part[(((size_t)c * B + b) * KVH + kvh) * 512 + hl * 128 + d];
  ctx[i] = s;
}

// ----------------------------------------------- output projection (M=16)
__global__ void k_wo(const float* __restrict__ ctx, const float* __restrict__ Wo,
                     float* __restrict__ part) {
  int n = blockIdx.x * 256 + threadIdx.x;  // < 4096
  int k0 = blockIdx.y * (D / WSPLIT);
  float acc[B];
#pragma unroll
  for (int b = 0; b < B; b++) acc[b] = 0.f;
  const float* wp = Wo + (size_t)k0 * D + n;
#pragma unroll 8
  for (int k = 0; k < D / WSPLIT; k++) {
    float wv = wp[(size_t)k * D];
#pragma unroll
    for (int b = 0; b < B; b++) acc[b] = fmaf(ctx[b * D + k0 + k], wv, acc[b]);
  }
  float* p = part + (size_t)blockIdx.y * (B * D);
#pragma unroll
  for (int b = 0; b < B; b++) p[(size_t)b * D + n] = acc[b];
}

__global__ void k_reduce_out(const float* __restrict__ part, float* __restrict__ out) {
  int i = blockIdx.x * 256 + threadIdx.x;  // < B*D
  float s = 0.f;
#pragma unroll
  for (int c = 0; c < WSPLIT; c++) s += part[(size_t)c * B * D + i];
  out[i] = s;
}

// ----------------------------------------------------------------- launch
extern "C" void kernel_launch(void* const* d_in, const int* in_sizes, int n_in,
                              void* d_out, int out_size, void* d_ws, size_t ws_size,
                              hipStream_t stream) {
  const float* hs    = (const float*)d_in[0];
  const int*   steps = (const int*)d_in[2];
  const float* cosb  = (const float*)d_in[3];
  const float* sinb  = (const float*)d_in[4];
  const float* pk    = (const float*)d_in[5];
  const float* pvv   = (const float*)d_in[6];
  const float* Wq    = (const float*)d_in[7];
  const float* Wk    = (const float*)d_in[8];
  const float* Wv    = (const float*)d_in[9];
  const float* Wo    = (const float*)d_in[10];

  float* attn_out = (float*)d_out;
  float* newk = attn_out + (size_t)B * D;
  float* newv = newk + (size_t)B * KVH * S * HD;

  float* ws = (float*)d_ws;
  // Region A (lifetimes disjoint): proj partials (3.1M) -> scores/probs (2.1M)
  //                                -> Wo partials (2.1M)
  float* A        = ws;                               // 3,145,728 floats
  float* p_part   = A;
  float* p_scores = A;
  float* p_wopart = A;
  float* p_pvpart = A + 3145728;                      // 1,048,576
  float* p_qr     = p_pvpart + 1048576;               //    65,536
  float* p_nkrow  = p_qr + (size_t)B * D;             //    16,384
  float* p_nvrow  = p_nkrow + (size_t)B * KVH * HD;   //    16,384
  float* p_ctx    = p_nvrow + (size_t)B * KVH * HD;   //    65,536

  hipLaunchKernelGGL(k_proj, dim3(NQKV / 256, PSPLIT), dim3(256), 0, stream,
                     hs, Wq, Wk, Wv, p_part);
  hipLaunchKernelGGL(k_reduce_rope, dim3(B * NQKV / 256), dim3(256), 0, stream,
                     p_part, cosb, sinb, steps, p_qr, p_nkrow, p_nvrow);
  hipLaunchKernelGGL(k_fusedK, dim3(NCH, KVH, B), dim3(256), 0, stream,
                     pk, p_nkrow, p_qr, steps, newk, p_scores);
  hipLaunchKernelGGL(k_smax, dim3(B * H), dim3(256), 0, stream,
                     p_scores, steps);
  hipLaunchKernelGGL(k_fusedV, dim3(NCH, KVH, B), dim3(256), 0, stream,
                     pvv, p_nvrow, p_scores, steps, newv, p_pvpart);
  hipLaunchKernelGGL(k_reduce_ctx, dim3(B * D / 256), dim3(256), 0, stream,
                     p_pvpart, p_ctx);
  hipLaunchKernelGGL(k_wo, dim3(D / 256, WSPLIT), dim3(256), 0, stream,
                     p_ctx, Wo, p_wopart);
  hipLaunchKernelGGL(k_reduce_out, dim3(B * D / 256), dim3(256), 0, stream,
                     p_wopart, attn_out);
}

// Round 10
// 308.974 us; speedup vs baseline: 1.1344x; 1.0258x over previous
//
#include <hip/hip_runtime.h>

#define B 16
#define H 32
#define KVH 8
#define HD 128
#define S 4096
#define D 4096
#define NQKV 6144   // 4096 q + 1024 k + 1024 v columns
#define PSPLIT 32   // k-split for QKV projection
#define WSPLIT 32   // k-split for Wo projection
#define NCH 16      // chunks per (b,kvh) panel
#define CROWS (S / NCH)  // 256 rows per chunk
#define SCALE 0.08838834764831845f  // 1/sqrt(128)

typedef float nfloat4 __attribute__((ext_vector_type(4)));

__device__ __forceinline__ float4 ntload4(const float4* p) {
  nfloat4 r = __builtin_nontemporal_load(reinterpret_cast<const nfloat4*>(p));
  return *reinterpret_cast<float4*>(&r);
}
__device__ __forceinline__ void ntstore4(float4* p, float4 v) {
  __builtin_nontemporal_store(*reinterpret_cast<nfloat4*>(&v),
                              reinterpret_cast<nfloat4*>(p));
}

// ------------------------------------------------- QKV projection (M=16 GEMM)
__global__ void k_proj(const float* __restrict__ hs, const float* __restrict__ Wq,
                       const float* __restrict__ Wk, const float* __restrict__ Wv,
                       float* __restrict__ part) {
  int n = blockIdx.x * 256 + threadIdx.x;
  int k0 = blockIdx.y * (D / PSPLIT);
  const float* w; int ldw, col;
  if (n < 4096)      { w = Wq; ldw = 4096; col = n; }
  else if (n < 5120) { w = Wk; ldw = 1024; col = n - 4096; }
  else               { w = Wv; ldw = 1024; col = n - 5120; }
  float acc[B];
#pragma unroll
  for (int b = 0; b < B; b++) acc[b] = 0.f;
  const float* wp = w + (size_t)k0 * ldw + col;
#pragma unroll 8
  for (int k = 0; k < D / PSPLIT; k++) {
    float wv = wp[(size_t)k * ldw];
#pragma unroll
    for (int b = 0; b < B; b++) acc[b] = fmaf(hs[b * D + k0 + k], wv, acc[b]);
  }
  float* p = part + (size_t)blockIdx.y * (B * NQKV);
#pragma unroll
  for (int b = 0; b < B; b++) p[(size_t)b * NQKV + n] = acc[b];
}

// ------------- reduce partials + RoPE (pairwise d,d+64) -> qr, new k/v rows
// thread handles one (d,d+64) pair for q/k, or one v column. B*3584 threads.
__global__ void k_reduce_rope(const float* __restrict__ part, const float* __restrict__ cosb,
                              const float* __restrict__ sinb, const int* __restrict__ steps,
                              float* __restrict__ qr, float* __restrict__ nkrow,
                              float* __restrict__ nvrow) {
  int i = blockIdx.x * 256 + threadIdx.x;  // < B*3584
  int b = i / 3584, n2 = i % 3584;
  if (n2 < 2560) {  // q/k pair
    int hr = n2 >> 6, d = n2 & 63;
    int n_lo = hr * 128 + d, n_hi = n_lo + 64;
    float vlo = 0.f, vhi = 0.f;
#pragma unroll
    for (int c = 0; c < PSPLIT; c++) {
      const float* pc = part + (size_t)c * B * NQKV + (size_t)b * NQKV;
      vlo += pc[n_lo];
      vhi += pc[n_hi];
    }
    float clo = cosb[b * HD + d], chi = cosb[b * HD + d + 64];
    float slo = sinb[b * HD + d], shi = sinb[b * HD + d + 64];
    float rlo = vlo * clo - vhi * slo;
    float rhi = vhi * chi + vlo * shi;
    if (n_lo < 4096) {
      qr[(size_t)b * D + n_lo] = rlo;
      qr[(size_t)b * D + n_hi] = rhi;
    } else {
      nkrow[(size_t)b * KVH * HD + (n_lo - 4096)] = rlo;
      nkrow[(size_t)b * KVH * HD + (n_hi - 4096)] = rhi;
    }
  } else {  // v column
    int j = n2 - 2560;
    float v = 0.f;
#pragma unroll
    for (int c = 0; c < PSPLIT; c++)
      v += part[(size_t)c * B * NQKV + (size_t)b * NQKV + 5120 + j];
    nvrow[(size_t)b * KVH * HD + j] = v;
  }
}

// ---- flash chunk kernel: K stream + scores -> LDS -> chunk-local softmax
// ---- stats -> V stream + PV accumulate. Split-S merge done in reduce_ctx.
__global__ void k_flashKV(const float* __restrict__ pastk, const float* __restrict__ pastv,
                          const float* __restrict__ nkrow, const float* __restrict__ nvrow,
                          const float* __restrict__ qr, const int* __restrict__ steps,
                          float* __restrict__ newk, float* __restrict__ newv,
                          float* __restrict__ part, float* __restrict__ stats) {
  int ch = blockIdx.x, kvh = blockIdx.y, b = blockIdx.z;
  int t = threadIdx.x;
  __shared__ float sbuf[CROWS][4];   // [row][head] scores -> probs
  __shared__ float redm[4][4];       // [wave][head]
  __shared__ float4 red4[4][4][32];  // [wave][head][d4]
  int s0 = ch * CROWS;
  int step = steps[b];
  int L = step + 1;
  int h0 = kvh * 4;
  bool any = (s0 < L);  // block-uniform
  int w = t >> 6;

  // ================= K phase: barrier-free stream, 16-lane row groups
  {
    int ln = t & 15, rg = t >> 4;
    const float4* qbase = (const float4*)(qr + ((size_t)b * H + h0) * HD);
    float4 q0[4], q1[4];
#pragma unroll
    for (int h = 0; h < 4; h++) {
      q0[h] = qbase[h * 32 + ln];
      q1[h] = qbase[h * 32 + ln + 16];
    }
    const float4* subp = (const float4*)(nkrow + (size_t)(b * KVH + kvh) * HD);
    float4 sub0 = subp[ln], sub1 = subp[ln + 16];
    const float4* src = (const float4*)(pastk + ((size_t)(b * KVH + kvh) * S + s0) * HD);
    float4*       dst = (float4*)(newk + ((size_t)(b * KVH + kvh) * S + s0) * HD);
#pragma unroll 4
    for (int it = 0; it < CROWS / 16; ++it) {
      int row = it * 16 + rg;
      size_t o0 = (size_t)row * 32 + ln;
      float4 k0 = ntload4(&src[o0]);
      float4 k1 = ntload4(&src[o0 + 16]);
      if (s0 + row == step) { k0 = sub0; k1 = sub1; }
      ntstore4(&dst[o0], k0);
      ntstore4(&dst[o0 + 16], k1);
      if (s0 + it * 16 < L) {  // wave-uniform skip of dead 16-row groups
        float a0, a1, a2, a3;
        a0 = fmaf(k0.x, q0[0].x, fmaf(k0.y, q0[0].y, fmaf(k0.z, q0[0].z, fmaf(k0.w, q0[0].w,
             fmaf(k1.x, q1[0].x, fmaf(k1.y, q1[0].y, fmaf(k1.z, q1[0].z, k1.w * q1[0].w)))))));
        a1 = fmaf(k0.x, q0[1].x, fmaf(k0.y, q0[1].y, fmaf(k0.z, q0[1].z, fmaf(k0.w, q0[1].w,
             fmaf(k1.x, q1[1].x, fmaf(k1.y, q1[1].y, fmaf(k1.z, q1[1].z, k1.w * q1[1].w)))))));
        a2 = fmaf(k0.x, q0[2].x, fmaf(k0.y, q0[2].y, fmaf(k0.z, q0[2].z, fmaf(k0.w, q0[2].w,
             fmaf(k1.x, q1[2].x, fmaf(k1.y, q1[2].y, fmaf(k1.z, q1[2].z, k1.w * q1[2].w)))))));
        a3 = fmaf(k0.x, q0[3].x, fmaf(k0.y, q0[3].y, fmaf(k0.z, q0[3].z, fmaf(k0.w, q0[3].w,
             fmaf(k1.x, q1[3].x, fmaf(k1.y, q1[3].y, fmaf(k1.z, q1[3].z, k1.w * q1[3].w)))))));
#pragma unroll
        for (int o = 1; o < 16; o <<= 1) {
          a0 += __shfl_xor(a0, o);
          a1 += __shfl_xor(a1, o);
          a2 += __shfl_xor(a2, o);
          a3 += __shfl_xor(a3, o);
        }
        if (ln < 4) {
          float my = (ln == 0) ? a0 : (ln == 1) ? a1 : (ln == 2) ? a2 : a3;
          sbuf[row][ln] = my * SCALE;
        }
      }
    }
  }
  __syncthreads();  // sbuf complete

  // ================= chunk-local softmax stats (m, l) + sbuf -> p
  bool valid = any && (s0 + t < L);
  float s_0 = valid ? sbuf[t][0] : -1e30f;
  float s_1 = valid ? sbuf[t][1] : -1e30f;
  float s_2 = valid ? sbuf[t][2] : -1e30f;
  float s_3 = valid ? sbuf[t][3] : -1e30f;
  float mx0 = s_0, mx1 = s_1, mx2 = s_2, mx3 = s_3;
#pragma unroll
  for (int o = 1; o < 64; o <<= 1) {
    mx0 = fmaxf(mx0, __shfl_xor(mx0, o));
    mx1 = fmaxf(mx1, __shfl_xor(mx1, o));
    mx2 = fmaxf(mx2, __shfl_xor(mx2, o));
    mx3 = fmaxf(mx3, __shfl_xor(mx3, o));
  }
  if ((t & 63) == 0) { redm[w][0] = mx0; redm[w][1] = mx1; redm[w][2] = mx2; redm[w][3] = mx3; }
  __syncthreads();
  float m0 = fmaxf(fmaxf(redm[0][0], redm[1][0]), fmaxf(redm[2][0], redm[3][0]));
  float m1 = fmaxf(fmaxf(redm[0][1], redm[1][1]), fmaxf(redm[2][1], redm[3][1]));
  float m2 = fmaxf(fmaxf(redm[0][2], redm[1][2]), fmaxf(redm[2][2], redm[3][2]));
  float m3 = fmaxf(fmaxf(redm[0][3], redm[1][3]), fmaxf(redm[2][3], redm[3][3]));
  float e0 = valid ? __expf(s_0 - m0) : 0.f;
  float e1 = valid ? __expf(s_1 - m1) : 0.f;
  float e2 = valid ? __expf(s_2 - m2) : 0.f;
  float e3 = valid ? __expf(s_3 - m3) : 0.f;
  float es0 = e0, es1 = e1, es2 = e2, es3 = e3;
#pragma unroll
  for (int o = 1; o < 64; o <<= 1) {
    es0 += __shfl_xor(es0, o);
    es1 += __shfl_xor(es1, o);
    es2 += __shfl_xor(es2, o);
    es3 += __shfl_xor(es3, o);
  }
  __syncthreads();  // done reading redm(max) before reuse
  if ((t & 63) == 0) { redm[w][0] = es0; redm[w][1] = es1; redm[w][2] = es2; redm[w][3] = es3; }
  sbuf[t][0] = e0; sbuf[t][1] = e1; sbuf[t][2] = e2; sbuf[t][3] = e3;
  __syncthreads();  // probs + sums ready
  float l0 = redm[0][0] + redm[1][0] + redm[2][0] + redm[3][0];
  float l1 = redm[0][1] + redm[1][1] + redm[2][1] + redm[3][1];
  float l2 = redm[0][2] + redm[1][2] + redm[2][2] + redm[3][2];
  float l3 = redm[0][3] + redm[1][3] + redm[2][3] + redm[3][3];

  // ================= V phase: barrier-free stream, (d4, rr) layout
  int d4 = t & 31, rr = t >> 5;
  float4 a0 = make_float4(0.f, 0.f, 0.f, 0.f), a1 = a0, a2 = a0, a3 = a0;
  {
    float4 vsub = ((const float4*)(nvrow + (size_t)(b * KVH + kvh) * HD))[d4];
    const float4* src = (const float4*)(pastv + ((size_t)(b * KVH + kvh) * S + s0) * HD);
    float4*       dst = (float4*)(newv + ((size_t)(b * KVH + kvh) * S + s0) * HD);
#pragma unroll 4
    for (int i = 0; i < CROWS / 8; ++i) {
      int r = i * 8 + rr;
      float4 v = ntload4(&src[r * 32 + d4]);
      if (s0 + r == step) v = vsub;
      ntstore4(&dst[r * 32 + d4], v);
      if (any && i * 8 < L - s0) {  // wave-uniform; probs zero-padded
        float q0 = sbuf[r][0], q1 = sbuf[r][1], q2 = sbuf[r][2], q3 = sbuf[r][3];
        a0.x = fmaf(q0, v.x, a0.x); a0.y = fmaf(q0, v.y, a0.y);
        a0.z = fmaf(q0, v.z, a0.z); a0.w = fmaf(q0, v.w, a0.w);
        a1.x = fmaf(q1, v.x, a1.x); a1.y = fmaf(q1, v.y, a1.y);
        a1.z = fmaf(q1, v.z, a1.z); a1.w = fmaf(q1, v.w, a1.w);
        a2.x = fmaf(q2, v.x, a2.x); a2.y = fmaf(q2, v.y, a2.y);
        a2.z = fmaf(q2, v.z, a2.z); a2.w = fmaf(q2, v.w, a2.w);
        a3.x = fmaf(q3, v.x, a3.x); a3.y = fmaf(q3, v.y, a3.y);
        a3.z = fmaf(q3, v.z, a3.z); a3.w = fmaf(q3, v.w, a3.w);
      }
    }
  }
  // combine rr pairs within wave (t^32 flips rr bit 0)
  a0.x += __shfl_xor(a0.x, 32); a0.y += __shfl_xor(a0.y, 32);
  a0.z += __shfl_xor(a0.z, 32); a0.w += __shfl_xor(a0.w, 32);
  a1.x += __shfl_xor(a1.x, 32); a1.y += __shfl_xor(a1.y, 32);
  a1.z += __shfl_xor(a1.z, 32); a1.w += __shfl_xor(a1.w, 32);
  a2.x += __shfl_xor(a2.x, 32); a2.y += __shfl_xor(a2.y, 32);
  a2.z += __shfl_xor(a2.z, 32); a2.w += __shfl_xor(a2.w, 32);
  a3.x += __shfl_xor(a3.x, 32); a3.y += __shfl_xor(a3.y, 32);
  a3.z += __shfl_xor(a3.z, 32); a3.w += __shfl_xor(a3.w, 32);
  __syncthreads();  // sbuf reads done before nothing; order waves for red4
  if ((t & 32) == 0) {
    red4[w][0][d4] = a0; red4[w][1][d4] = a1; red4[w][2][d4] = a2; red4[w][3][d4] = a3;
  }
  __syncthreads();
  if (t < 128) {
    int hh = t >> 5, dd = t & 31;
    float4 x0 = red4[0][hh][dd], x1 = red4[1][hh][dd], x2 = red4[2][hh][dd], x3 = red4[3][hh][dd];
    float4 s;
    s.x = (x0.x + x1.x) + (x2.x + x3.x);
    s.y = (x0.y + x1.y) + (x2.y + x3.y);
    s.z = (x0.z + x1.z) + (x2.z + x3.z);
    s.w = (x0.w + x1.w) + (x2.w + x3.w);
    ((float4*)(part + (((size_t)ch * B + b) * KVH + kvh) * 512))[t] = s;
  }
  if (t == 0) {
    size_t si = (((size_t)ch * B + b) * KVH + kvh) * 8;
    stats[si + 0] = m0; stats[si + 1] = l0;
    stats[si + 2] = m1; stats[si + 3] = l1;
    stats[si + 4] = m2; stats[si + 5] = l2;
    stats[si + 6] = m3; stats[si + 7] = l3;
  }
}

// ------------- split-S merge: ctx = sum(e^{m-M} acc) / sum(e^{m-M} l)
__global__ void k_reduce_ctx(const float* __restrict__ part, const float* __restrict__ stats,
                             float* __restrict__ ctx) {
  int i = blockIdx.x * 256 + threadIdx.x;  // < B*D
  int b = i >> 12, r = i & 4095, h = r >> 7, d = r & 127;
  int kvh = h >> 2, hl = h & 3;
  float M = -1e30f;
#pragma unroll
  for (int c = 0; c < NCH; c++)
    M = fmaxf(M, stats[(((size_t)c * B + b) * KVH + kvh) * 8 + hl * 2]);
  float num = 0.f, den = 0.f;
#pragma unroll
  for (int c = 0; c < NCH; c++) {
    size_t si = (((size_t)c * B + b) * KVH + kvh) * 8 + hl * 2;
    float wgt = __expf(stats[si] - M);
    den += wgt * stats[si + 1];
    num += wgt * part[(((size_t)c * B + b) * KVH + kvh) * 512 + hl * 128 + d];
  }
  ctx[i] = num / den;
}

// ----------------------------------------------- output projection (M=16)
__global__ void k_wo(const float* __restrict__ ctx, const float* __restrict__ Wo,
                     float* __restrict__ part) {
  int n = blockIdx.x * 256 + threadIdx.x;  // < 4096
  int k0 = blockIdx.y * (D / WSPLIT);
  float acc[B];
#pragma unroll
  for (int b = 0; b < B; b++) acc[b] = 0.f;
  const float* wp = Wo + (size_t)k0 * D + n;
#pragma unroll 8
  for (int k = 0; k < D / WSPLIT; k++) {
    float wv = wp[(size_t)k * D];
#pragma unroll
    for (int b = 0; b < B; b++) acc[b] = fmaf(ctx[b * D + k0 + k], wv, acc[b]);
  }
  float* p = part + (size_t)blockIdx.y * (B * D);
#pragma unroll
  for (int b = 0; b < B; b++) p[(size_t)b * D + n] = acc[b];
}

__global__ void k_reduce_out(const float* __restrict__ part, float* __restrict__ out) {
  int i = blockIdx.x * 256 + threadIdx.x;  // < B*D
  float s = 0.f;
#pragma unroll
  for (int c = 0; c < WSPLIT; c++) s += part[(size_t)c * B * D + i];
  out[i] = s;
}

// ----------------------------------------------------------------- launch
extern "C" void kernel_launch(void* const* d_in, const int* in_sizes, int n_in,
                              void* d_out, int out_size, void* d_ws, size_t ws_size,
                              hipStream_t stream) {
  const float* hs    = (const float*)d_in[0];
  const int*   steps = (const int*)d_in[2];
  const float* cosb  = (const float*)d_in[3];
  const float* sinb  = (const float*)d_in[4];
  const float* pk    = (const float*)d_in[5];
  const float* pvv   = (const float*)d_in[6];
  const float* Wq    = (const float*)d_in[7];
  const float* Wk    = (const float*)d_in[8];
  const float* Wv    = (const float*)d_in[9];
  const float* Wo    = (const float*)d_in[10];

  float* attn_out = (float*)d_out;
  float* newk = attn_out + (size_t)B * D;
  float* newv = newk + (size_t)B * KVH * S * HD;

  float* ws = (float*)d_ws;
  // Region A (lifetimes disjoint): proj partials (3.1M) -> Wo partials (2.1M)
  float* A        = ws;                               // 3,145,728 floats
  float* p_part   = A;
  float* p_wopart = A;
  float* p_pvpart = A + 3145728;                      // 1,048,576
  float* p_stats  = p_pvpart + 1048576;               //    16,384
  float* p_qr     = p_stats + 16384;                  //    65,536
  float* p_nkrow  = p_qr + (size_t)B * D;             //    16,384
  float* p_nvrow  = p_nkrow + (size_t)B * KVH * HD;   //    16,384
  float* p_ctx    = p_nvrow + (size_t)B * KVH * HD;   //    65,536

  hipLaunchKernelGGL(k_proj, dim3(NQKV / 256, PSPLIT), dim3(256), 0, stream,
                     hs, Wq, Wk, Wv, p_part);
  hipLaunchKernelGGL(k_reduce_rope, dim3(B * 3584 / 256), dim3(256), 0, stream,
                     p_part, cosb, sinb, steps, p_qr, p_nkrow, p_nvrow);
  hipLaunchKernelGGL(k_flashKV, dim3(NCH, KVH, B), dim3(256), 0, stream,
                     pk, pvv, p_nkrow, p_nvrow, p_qr, steps, newk, newv,
                     p_pvpart, p_stats);
  hipLaunchKernelGGL(k_reduce_ctx, dim3(B * D / 256), dim3(256), 0, stream,
                     p_pvpart, p_stats, p_ctx);
  hipLaunchKernelGGL(k_wo, dim3(D / 256, WSPLIT), dim3(256), 0, stream,
                     p_ctx, Wo, p_wopart);
  hipLaunchKernelGGL(k_reduce_out, dim3(B * D / 256), dim3(256), 0, stream,
                     p_wopart, attn_out);
}

// Round 11
// 303.376 us; speedup vs baseline: 1.1553x; 1.0185x over previous
//
#include <hip/hip_runtime.h>

#define B 16
#define H 32
#define KVH 8
#define HD 128
#define S 4096
#define D 4096
#define NQKV 6144   // 4096 q + 1024 k + 1024 v columns
#define PSPLIT 32   // k-split for QKV projection
#define WSPLIT 32   // k-split for Wo projection
#define NCH 16      // chunks per (b,kvh) panel
#define CROWS (S / NCH)  // 256 rows per chunk
#define SCALE 0.08838834764831845f  // 1/sqrt(128)

typedef float nfloat4 __attribute__((ext_vector_type(4)));

__device__ __forceinline__ float4 ntload4(const float4* p) {
  nfloat4 r = __builtin_nontemporal_load(reinterpret_cast<const nfloat4*>(p));
  return *reinterpret_cast<float4*>(&r);
}
__device__ __forceinline__ void ntstore4(float4* p, float4 v) {
  __builtin_nontemporal_store(*reinterpret_cast<nfloat4*>(&v),
                              reinterpret_cast<nfloat4*>(p));
}
__device__ __forceinline__ float ntloadf(const float* p) {
  return __builtin_nontemporal_load(p);
}

// ------------------------------------------------- QKV projection (M=16 GEMM)
__global__ void k_proj(const float* __restrict__ hs, const float* __restrict__ Wq,
                       const float* __restrict__ Wk, const float* __restrict__ Wv,
                       float* __restrict__ part) {
  int n = blockIdx.x * 256 + threadIdx.x;
  int k0 = blockIdx.y * (D / PSPLIT);
  const float* w; int ldw, col;
  if (n < 4096)      { w = Wq; ldw = 4096; col = n; }
  else if (n < 5120) { w = Wk; ldw = 1024; col = n - 4096; }
  else               { w = Wv; ldw = 1024; col = n - 5120; }
  float acc[B];
#pragma unroll
  for (int b = 0; b < B; b++) acc[b] = 0.f;
  const float* wp = w + (size_t)k0 * ldw + col;
#pragma unroll 8
  for (int k = 0; k < D / PSPLIT; k++) {
    float wv = ntloadf(&wp[(size_t)k * ldw]);  // weights read exactly once
#pragma unroll
    for (int b = 0; b < B; b++) acc[b] = fmaf(hs[b * D + k0 + k], wv, acc[b]);
  }
  float* p = part + (size_t)blockIdx.y * (B * NQKV);
#pragma unroll
  for (int b = 0; b < B; b++) p[(size_t)b * NQKV + n] = acc[b];  // cacheable: consumer L2-hits
}

// ------------- reduce partials + RoPE (pairwise d,d+64) -> qr, new k/v rows
__global__ void k_reduce_rope(const float* __restrict__ part, const float* __restrict__ cosb,
                              const float* __restrict__ sinb, const int* __restrict__ steps,
                              float* __restrict__ qr, float* __restrict__ nkrow,
                              float* __restrict__ nvrow) {
  int i = blockIdx.x * 256 + threadIdx.x;  // < B*3584
  int b = i / 3584, n2 = i % 3584;
  if (n2 < 2560) {  // q/k pair
    int hr = n2 >> 6, d = n2 & 63;
    int n_lo = hr * 128 + d, n_hi = n_lo + 64;
    float vlo = 0.f, vhi = 0.f;
#pragma unroll
    for (int c = 0; c < PSPLIT; c++) {
      const float* pc = part + (size_t)c * B * NQKV + (size_t)b * NQKV;
      vlo += ntloadf(&pc[n_lo]);
      vhi += ntloadf(&pc[n_hi]);
    }
    float clo = cosb[b * HD + d], chi = cosb[b * HD + d + 64];
    float slo = sinb[b * HD + d], shi = sinb[b * HD + d + 64];
    float rlo = vlo * clo - vhi * slo;
    float rhi = vhi * chi + vlo * shi;
    if (n_lo < 4096) {
      qr[(size_t)b * D + n_lo] = rlo;
      qr[(size_t)b * D + n_hi] = rhi;
    } else {
      nkrow[(size_t)b * KVH * HD + (n_lo - 4096)] = rlo;
      nkrow[(size_t)b * KVH * HD + (n_hi - 4096)] = rhi;
    }
  } else {  // v column
    int j = n2 - 2560;
    float v = 0.f;
#pragma unroll
    for (int c = 0; c < PSPLIT; c++)
      v += ntloadf(&part[(size_t)c * B * NQKV + (size_t)b * NQKV + 5120 + j]);
    nvrow[(size_t)b * KVH * HD + j] = v;
  }
}

// ---- flash chunk kernel: K stream + scores -> LDS -> chunk-local softmax
// ---- (3 barriers) -> V stream (2 rows/iter, prefetched through stats) + PV.
__global__ void __launch_bounds__(256)
k_flashKV(const float* __restrict__ pastk, const float* __restrict__ pastv,
          const float* __restrict__ nkrow, const float* __restrict__ nvrow,
          const float* __restrict__ qr, const int* __restrict__ steps,
          float* __restrict__ newk, float* __restrict__ newv,
          float* __restrict__ part, float* __restrict__ stats) {
  int ch = blockIdx.x, kvh = blockIdx.y, b = blockIdx.z;
  int t = threadIdx.x;
  __shared__ float sbuf[CROWS][4];   // [row][head] scores -> probs
  __shared__ float redmx[4][4];      // [wave][head] max partials
  __shared__ float redsm[4][4];      // [wave][head] sum partials
  __shared__ float4 red4[4][4][32];  // [wave][head][d4]
  int s0 = ch * CROWS;
  int step = steps[b];
  int L = step + 1;
  int h0 = kvh * 4;
  bool any = (s0 < L);  // block-uniform
  int w = t >> 6;
  int d4 = t & 31, rr = t >> 5;  // V-phase / staging layout

  const float4* srcv = (const float4*)(pastv + ((size_t)(b * KVH + kvh) * S + s0) * HD);
  float4*       dstv = (float4*)(newv + ((size_t)(b * KVH + kvh) * S + s0) * HD);
  float4 vsub = ((const float4*)(nvrow + (size_t)(b * KVH + kvh) * HD))[d4];

  // ================= K phase: barrier-free stream, 16-lane row groups
  {
    int ln = t & 15, rg = t >> 4;
    const float4* qbase = (const float4*)(qr + ((size_t)b * H + h0) * HD);
    float4 q0[4], q1[4];
#pragma unroll
    for (int h = 0; h < 4; h++) {
      q0[h] = qbase[h * 32 + ln];
      q1[h] = qbase[h * 32 + ln + 16];
    }
    const float4* subp = (const float4*)(nkrow + (size_t)(b * KVH + kvh) * HD);
    float4 sub0 = subp[ln], sub1 = subp[ln + 16];
    const float4* src = (const float4*)(pastk + ((size_t)(b * KVH + kvh) * S + s0) * HD);
    float4*       dst = (float4*)(newk + ((size_t)(b * KVH + kvh) * S + s0) * HD);
#pragma unroll 4
    for (int it = 0; it < CROWS / 16; ++it) {
      int row = it * 16 + rg;
      size_t o0 = (size_t)row * 32 + ln;
      float4 k0 = ntload4(&src[o0]);
      float4 k1 = ntload4(&src[o0 + 16]);
      if (s0 + row == step) { k0 = sub0; k1 = sub1; }
      ntstore4(&dst[o0], k0);
      ntstore4(&dst[o0 + 16], k1);
      if (s0 + it * 16 < L) {  // wave-uniform skip of dead 16-row groups
        float a0, a1, a2, a3;
        a0 = fmaf(k0.x, q0[0].x, fmaf(k0.y, q0[0].y, fmaf(k0.z, q0[0].z, fmaf(k0.w, q0[0].w,
             fmaf(k1.x, q1[0].x, fmaf(k1.y, q1[0].y, fmaf(k1.z, q1[0].z, k1.w * q1[0].w)))))));
        a1 = fmaf(k0.x, q0[1].x, fmaf(k0.y, q0[1].y, fmaf(k0.z, q0[1].z, fmaf(k0.w, q0[1].w,
             fmaf(k1.x, q1[1].x, fmaf(k1.y, q1[1].y, fmaf(k1.z, q1[1].z, k1.w * q1[1].w)))))));
        a2 = fmaf(k0.x, q0[2].x, fmaf(k0.y, q0[2].y, fmaf(k0.z, q0[2].z, fmaf(k0.w, q0[2].w,
             fmaf(k1.x, q1[2].x, fmaf(k1.y, q1[2].y, fmaf(k1.z, q1[2].z, k1.w * q1[2].w)))))));
        a3 = fmaf(k0.x, q0[3].x, fmaf(k0.y, q0[3].y, fmaf(k0.z, q0[3].z, fmaf(k0.w, q0[3].w,
             fmaf(k1.x, q1[3].x, fmaf(k1.y, q1[3].y, fmaf(k1.z, q1[3].z, k1.w * q1[3].w)))))));
#pragma unroll
        for (int o = 1; o < 16; o <<= 1) {
          a0 += __shfl_xor(a0, o);
          a1 += __shfl_xor(a1, o);
          a2 += __shfl_xor(a2, o);
          a3 += __shfl_xor(a3, o);
        }
        if (ln < 4) {
          float my = (ln == 0) ? a0 : (ln == 1) ? a1 : (ln == 2) ? a2 : a3;
          sbuf[row][ln] = my * SCALE;
        }
      }
    }
  }
  // prefetch first V row-pair: loads stay in flight across the stats barriers
  float4 pv0 = ntload4(&srcv[(size_t)rr * 32 + d4]);
  float4 pv1 = ntload4(&srcv[(size_t)(rr + 8) * 32 + d4]);
  __syncthreads();  // A: sbuf complete

  // ================= chunk-local softmax stats (m, l), sbuf -> p, 3 barriers
  bool valid = any && (s0 + t < L);
  float s_0 = valid ? sbuf[t][0] : -1e30f;
  float s_1 = valid ? sbuf[t][1] : -1e30f;
  float s_2 = valid ? sbuf[t][2] : -1e30f;
  float s_3 = valid ? sbuf[t][3] : -1e30f;
  float mx0 = s_0, mx1 = s_1, mx2 = s_2, mx3 = s_3;
#pragma unroll
  for (int o = 1; o < 64; o <<= 1) {
    mx0 = fmaxf(mx0, __shfl_xor(mx0, o));
    mx1 = fmaxf(mx1, __shfl_xor(mx1, o));
    mx2 = fmaxf(mx2, __shfl_xor(mx2, o));
    mx3 = fmaxf(mx3, __shfl_xor(mx3, o));
  }
  if ((t & 63) == 0) { redmx[w][0] = mx0; redmx[w][1] = mx1; redmx[w][2] = mx2; redmx[w][3] = mx3; }
  __syncthreads();  // B: wave maxes ready
  float m0 = fmaxf(fmaxf(redmx[0][0], redmx[1][0]), fmaxf(redmx[2][0], redmx[3][0]));
  float m1 = fmaxf(fmaxf(redmx[0][1], redmx[1][1]), fmaxf(redmx[2][1], redmx[3][1]));
  float m2 = fmaxf(fmaxf(redmx[0][2], redmx[1][2]), fmaxf(redmx[2][2], redmx[3][2]));
  float m3 = fmaxf(fmaxf(redmx[0][3], redmx[1][3]), fmaxf(redmx[2][3], redmx[3][3]));
  float e0 = valid ? __expf(s_0 - m0) : 0.f;
  float e1 = valid ? __expf(s_1 - m1) : 0.f;
  float e2 = valid ? __expf(s_2 - m2) : 0.f;
  float e3 = valid ? __expf(s_3 - m3) : 0.f;
  float es0 = e0, es1 = e1, es2 = e2, es3 = e3;
#pragma unroll
  for (int o = 1; o < 64; o <<= 1) {
    es0 += __shfl_xor(es0, o);
    es1 += __shfl_xor(es1, o);
    es2 += __shfl_xor(es2, o);
    es3 += __shfl_xor(es3, o);
  }
  if ((t & 63) == 0) { redsm[w][0] = es0; redsm[w][1] = es1; redsm[w][2] = es2; redsm[w][3] = es3; }
  sbuf[t][0] = e0; sbuf[t][1] = e1; sbuf[t][2] = e2; sbuf[t][3] = e3;  // own row only
  __syncthreads();  // C: probs + wave sums ready
  float l0 = redsm[0][0] + redsm[1][0] + redsm[2][0] + redsm[3][0];
  float l1 = redsm[0][1] + redsm[1][1] + redsm[2][1] + redsm[3][1];
  float l2 = redsm[0][2] + redsm[1][2] + redsm[2][2] + redsm[3][2];
  float l3 = redsm[0][3] + redsm[1][3] + redsm[2][3] + redsm[3][3];

  // ================= V phase: barrier-free stream, 2 rows/iter, prefetched
  float4 a0 = make_float4(0.f, 0.f, 0.f, 0.f), a1 = a0, a2 = a0, a3 = a0;
#pragma unroll 2
  for (int i = 0; i < CROWS / 16; ++i) {
    int r0 = i * 16 + rr, r1 = r0 + 8;
    float4 v0 = pv0, v1 = pv1;
    if (i + 1 < CROWS / 16) {
      pv0 = ntload4(&srcv[(size_t)(r0 + 16) * 32 + d4]);
      pv1 = ntload4(&srcv[(size_t)(r1 + 16) * 32 + d4]);
    }
    if (s0 + r0 == step) v0 = vsub;
    if (s0 + r1 == step) v1 = vsub;
    ntstore4(&dstv[(size_t)r0 * 32 + d4], v0);
    ntstore4(&dstv[(size_t)r1 * 32 + d4], v1);
    if (any && i * 16 < L - s0) {  // block-uniform; probs zero-padded
      float p00 = sbuf[r0][0], p01 = sbuf[r0][1], p02 = sbuf[r0][2], p03 = sbuf[r0][3];
      float p10 = sbuf[r1][0], p11 = sbuf[r1][1], p12 = sbuf[r1][2], p13 = sbuf[r1][3];
      a0.x = fmaf(p00, v0.x, fmaf(p10, v1.x, a0.x));
      a0.y = fmaf(p00, v0.y, fmaf(p10, v1.y, a0.y));
      a0.z = fmaf(p00, v0.z, fmaf(p10, v1.z, a0.z));
      a0.w = fmaf(p00, v0.w, fmaf(p10, v1.w, a0.w));
      a1.x = fmaf(p01, v0.x, fmaf(p11, v1.x, a1.x));
      a1.y = fmaf(p01, v0.y, fmaf(p11, v1.y, a1.y));
      a1.z = fmaf(p01, v0.z, fmaf(p11, v1.z, a1.z));
      a1.w = fmaf(p01, v0.w, fmaf(p11, v1.w, a1.w));
      a2.x = fmaf(p02, v0.x, fmaf(p12, v1.x, a2.x));
      a2.y = fmaf(p02, v0.y, fmaf(p12, v1.y, a2.y));
      a2.z = fmaf(p02, v0.z, fmaf(p12, v1.z, a2.z));
      a2.w = fmaf(p02, v0.w, fmaf(p12, v1.w, a2.w));
      a3.x = fmaf(p03, v0.x, fmaf(p13, v1.x, a3.x));
      a3.y = fmaf(p03, v0.y, fmaf(p13, v1.y, a3.y));
      a3.z = fmaf(p03, v0.z, fmaf(p13, v1.z, a3.z));
      a3.w = fmaf(p03, v0.w, fmaf(p13, v1.w, a3.w));
    }
  }
  // combine rr pairs within wave (t^32 flips rr bit 0)
  a0.x += __shfl_xor(a0.x, 32); a0.y += __shfl_xor(a0.y, 32);
  a0.z += __shfl_xor(a0.z, 32); a0.w += __shfl_xor(a0.w, 32);
  a1.x += __shfl_xor(a1.x, 32); a1.y += __shfl_xor(a1.y, 32);
  a1.z += __shfl_xor(a1.z, 32); a1.w += __shfl_xor(a1.w, 32);
  a2.x += __shfl_xor(a2.x, 32); a2.y += __shfl_xor(a2.y, 32);
  a2.z += __shfl_xor(a2.z, 32); a2.w += __shfl_xor(a2.w, 32);
  a3.x += __shfl_xor(a3.x, 32); a3.y += __shfl_xor(a3.y, 32);
  a3.z += __shfl_xor(a3.z, 32); a3.w += __shfl_xor(a3.w, 32);
  if ((t & 32) == 0) {
    red4[w][0][d4] = a0; red4[w][1][d4] = a1; red4[w][2][d4] = a2; red4[w][3][d4] = a3;
  }
  __syncthreads();  // D: partials ready
  if (t < 128) {
    int hh = t >> 5, dd = t & 31;
    float4 x0 = red4[0][hh][dd], x1 = red4[1][hh][dd], x2 = red4[2][hh][dd], x3 = red4[3][hh][dd];
    float4 s;
    s.x = (x0.x + x1.x) + (x2.x + x3.x);
    s.y = (x0.y + x1.y) + (x2.y + x3.y);
    s.z = (x0.z + x1.z) + (x2.z + x3.z);
    s.w = (x0.w + x1.w) + (x2.w + x3.w);
    ((float4*)(part + (((size_t)ch * B + b) * KVH + kvh) * 512))[t] = s;
  }
  if (t == 0) {
    size_t si = (((size_t)ch * B + b) * KVH + kvh) * 8;
    stats[si + 0] = m0; stats[si + 1] = l0;
    stats[si + 2] = m1; stats[si + 3] = l1;
    stats[si + 4] = m2; stats[si + 5] = l2;
    stats[si + 6] = m3; stats[si + 7] = l3;
  }
}

// ------------- split-S merge: ctx = sum(e^{m-M} acc) / sum(e^{m-M} l)
__global__ void k_reduce_ctx(const float* __restrict__ part, const float* __restrict__ stats,
                             float* __restrict__ ctx) {
  int i = blockIdx.x * 256 + threadIdx.x;  // < B*D
  int b = i >> 12, r = i & 4095, h = r >> 7, d = r & 127;
  int kvh = h >> 2, hl = h & 3;
  float M = -1e30f;
#pragma unroll
  for (int c = 0; c < NCH; c++)
    M = fmaxf(M, stats[(((size_t)c * B + b) * KVH + kvh) * 8 + hl * 2]);
  float num = 0.f, den = 0.f;
#pragma unroll
  for (int c = 0; c < NCH; c++) {
    size_t si = (((size_t)c * B + b) * KVH + kvh) * 8 + hl * 2;
    float wgt = __expf(stats[si] - M);
    den += wgt * stats[si + 1];
    num += wgt * part[(((size_t)c * B + b) * KVH + kvh) * 512 + hl * 128 + d];
  }
  ctx[i] = num / den;
}

// ----------------------------------------------- output projection (M=16)
__global__ void k_wo(const float* __restrict__ ctx, const float* __restrict__ Wo,
                     float* __restrict__ part) {
  int n = blockIdx.x * 256 + threadIdx.x;  // < 4096
  int k0 = blockIdx.y * (D / WSPLIT);
  float acc[B];
#pragma unroll
  for (int b = 0; b < B; b++) acc[b] = 0.f;
  const float* wp = Wo + (size_t)k0 * D + n;
#pragma unroll 8
  for (int k = 0; k < D / WSPLIT; k++) {
    float wv = ntloadf(&wp[(size_t)k * D]);  // Wo read exactly once
#pragma unroll
    for (int b = 0; b < B; b++) acc[b] = fmaf(ctx[b * D + k0 + k], wv, acc[b]);
  }
  float* p = part + (size_t)blockIdx.y * (B * D);
#pragma unroll
  for (int b = 0; b < B; b++) p[(size_t)b * D + n] = acc[b];  // cacheable
}

__global__ void k_reduce_out(const float* __restrict__ part, float* __restrict__ out) {
  int i = blockIdx.x * 256 + threadIdx.x;  // < B*D
  float s = 0.f;
#pragma unroll
  for (int c = 0; c < WSPLIT; c++) s += part[(size_t)c * B * D + i];
  out[i] = s;
}

// ----------------------------------------------------------------- launch
extern "C" void kernel_launch(void* const* d_in, const int* in_sizes, int n_in,
                              void* d_out, int out_size, void* d_ws, size_t ws_size,
                              hipStream_t stream) {
  const float* hs    = (const float*)d_in[0];
  const int*   steps = (const int*)d_in[2];
  const float* cosb  = (const float*)d_in[3];
  const float* sinb  = (const float*)d_in[4];
  const float* pk    = (const float*)d_in[5];
  const float* pvv   = (const float*)d_in[6];
  const float* Wq    = (const float*)d_in[7];
  const float* Wk    = (const float*)d_in[8];
  const float* Wv    = (const float*)d_in[9];
  const float* Wo    = (const float*)d_in[10];

  float* attn_out = (float*)d_out;
  float* newk = attn_out + (size_t)B * D;
  float* newv = newk + (size_t)B * KVH * S * HD;

  float* ws = (float*)d_ws;
  // Region A (lifetimes disjoint): proj partials (3.1M) -> Wo partials (2.1M)
  float* A        = ws;                               // 3,145,728 floats
  float* p_part   = A;
  float* p_wopart = A;
  float* p_pvpart = A + 3145728;                      // 1,048,576
  float* p_stats  = p_pvpart + 1048576;               //    16,384
  float* p_qr     = p_stats + 16384;                  //    65,536
  float* p_nkrow  = p_qr + (size_t)B * D;             //    16,384
  float* p_nvrow  = p_nkrow + (size_t)B * KVH * HD;   //    16,384
  float* p_ctx    = p_nvrow + (size_t)B * KVH * HD;   //    65,536

  hipLaunchKernelGGL(k_proj, dim3(NQKV / 256, PSPLIT), dim3(256), 0, stream,
                     hs, Wq, Wk, Wv, p_part);
  hipLaunchKernelGGL(k_reduce_rope, dim3(B * 3584 / 256), dim3(256), 0, stream,
                     p_part, cosb, sinb, steps, p_qr, p_nkrow, p_nvrow);
  hipLaunchKernelGGL(k_flashKV, dim3(NCH, KVH, B), dim3(256), 0, stream,
                     pk, pvv, p_nkrow, p_nvrow, p_qr, steps, newk, newv,
                     p_pvpart, p_stats);
  hipLaunchKernelGGL(k_reduce_ctx, dim3(B * D / 256), dim3(256), 0, stream,
                     p_pvpart, p_stats, p_ctx);
  hipLaunchKernelGGL(k_wo, dim3(D / 256, WSPLIT), dim3(256), 0, stream,
                     p_ctx, Wo, p_wopart);
  hipLaunchKernelGGL(k_reduce_out, dim3(B * D / 256), dim3(256), 0, stream,
                     p_wopart, attn_out);
}

// Round 12
// 291.219 us; speedup vs baseline: 1.2035x; 1.0417x over previous
//
#include <hip/hip_runtime.h>

#define B 16
#define H 32
#define KVH 8
#define HD 128
#define S 4096
#define D 4096
#define NQKV 6144   // 4096 q + 1024 k + 1024 v columns
#define PSPLIT 32   // k-split for QKV projection
#define WSPLIT 32   // k-split for Wo projection
#define NCH 16      // chunks per (b,kvh) panel
#define CROWS (S / NCH)  // 256 rows per chunk
#define SCALE 0.08838834764831845f  // 1/sqrt(128)

typedef float nfloat4 __attribute__((ext_vector_type(4)));

__device__ __forceinline__ float4 ntload4(const float4* p) {
  nfloat4 r = __builtin_nontemporal_load(reinterpret_cast<const nfloat4*>(p));
  return *reinterpret_cast<float4*>(&r);
}
__device__ __forceinline__ float ntloadf(const float* p) {
  return __builtin_nontemporal_load(p);
}

// ------------------------------------------------- QKV projection (M=16 GEMM)
// Activations staged transposed in LDS (hsT[k][b4]) so the inner loop has no
// wave-uniform scalar-load chain: 1 NT weight load + 4 broadcast ds_read_b128
// + 16 FMA per k.
__global__ void k_proj(const float* __restrict__ hs, const float* __restrict__ Wq,
                       const float* __restrict__ Wk, const float* __restrict__ Wv,
                       float* __restrict__ part) {
  __shared__ float4 hsT[D / PSPLIT][4];  // [k][b4] : 8 KB
  int t = threadIdx.x;
  int n = blockIdx.x * 256 + t;
  int k0 = blockIdx.y * (D / PSPLIT);
#pragma unroll
  for (int i = 0; i < (D / PSPLIT) * 4 / 256; i++) {
    int idx = i * 256 + t;          // 0..511
    int k = idx >> 2, b4 = idx & 3;
    hsT[k][b4] = make_float4(hs[(size_t)(b4 * 4 + 0) * D + k0 + k],
                             hs[(size_t)(b4 * 4 + 1) * D + k0 + k],
                             hs[(size_t)(b4 * 4 + 2) * D + k0 + k],
                             hs[(size_t)(b4 * 4 + 3) * D + k0 + k]);
  }
  const float* w; int ldw, col;
  if (n < 4096)      { w = Wq; ldw = 4096; col = n; }
  else if (n < 5120) { w = Wk; ldw = 1024; col = n - 4096; }
  else               { w = Wv; ldw = 1024; col = n - 5120; }
  float acc[B];
#pragma unroll
  for (int b = 0; b < B; b++) acc[b] = 0.f;
  const float* wp = w + (size_t)k0 * ldw + col;
  __syncthreads();
#pragma unroll 4
  for (int k = 0; k < D / PSPLIT; k++) {
    float wv = ntloadf(&wp[(size_t)k * ldw]);  // weights read exactly once
    float4 h0 = hsT[k][0], h1 = hsT[k][1], h2 = hsT[k][2], h3 = hsT[k][3];
    acc[0]  = fmaf(h0.x, wv, acc[0]);  acc[1]  = fmaf(h0.y, wv, acc[1]);
    acc[2]  = fmaf(h0.z, wv, acc[2]);  acc[3]  = fmaf(h0.w, wv, acc[3]);
    acc[4]  = fmaf(h1.x, wv, acc[4]);  acc[5]  = fmaf(h1.y, wv, acc[5]);
    acc[6]  = fmaf(h1.z, wv, acc[6]);  acc[7]  = fmaf(h1.w, wv, acc[7]);
    acc[8]  = fmaf(h2.x, wv, acc[8]);  acc[9]  = fmaf(h2.y, wv, acc[9]);
    acc[10] = fmaf(h2.z, wv, acc[10]); acc[11] = fmaf(h2.w, wv, acc[11]);
    acc[12] = fmaf(h3.x, wv, acc[12]); acc[13] = fmaf(h3.y, wv, acc[13]);
    acc[14] = fmaf(h3.z, wv, acc[14]); acc[15] = fmaf(h3.w, wv, acc[15]);
  }
  float* p = part + (size_t)blockIdx.y * (B * NQKV);
#pragma unroll
  for (int b = 0; b < B; b++) p[(size_t)b * NQKV + n] = acc[b];  // cacheable
}

// ------------- reduce partials + RoPE (pairwise d,d+64) -> qr, new k/v rows
__global__ void k_reduce_rope(const float* __restrict__ part, const float* __restrict__ cosb,
                              const float* __restrict__ sinb, const int* __restrict__ steps,
                              float* __restrict__ qr, float* __restrict__ nkrow,
                              float* __restrict__ nvrow) {
  int i = blockIdx.x * 256 + threadIdx.x;  // < B*3584
  int b = i / 3584, n2 = i % 3584;
  if (n2 < 2560) {  // q/k pair
    int hr = n2 >> 6, d = n2 & 63;
    int n_lo = hr * 128 + d, n_hi = n_lo + 64;
    float vlo = 0.f, vhi = 0.f;
#pragma unroll
    for (int c = 0; c < PSPLIT; c++) {
      const float* pc = part + (size_t)c * B * NQKV + (size_t)b * NQKV;
      vlo += ntloadf(&pc[n_lo]);
      vhi += ntloadf(&pc[n_hi]);
    }
    float clo = cosb[b * HD + d], chi = cosb[b * HD + d + 64];
    float slo = sinb[b * HD + d], shi = sinb[b * HD + d + 64];
    float rlo = vlo * clo - vhi * slo;
    float rhi = vhi * chi + vlo * shi;
    if (n_lo < 4096) {
      qr[(size_t)b * D + n_lo] = rlo;
      qr[(size_t)b * D + n_hi] = rhi;
    } else {
      nkrow[(size_t)b * KVH * HD + (n_lo - 4096)] = rlo;
      nkrow[(size_t)b * KVH * HD + (n_hi - 4096)] = rhi;
    }
  } else {  // v column
    int j = n2 - 2560;
    float v = 0.f;
#pragma unroll
    for (int c = 0; c < PSPLIT; c++)
      v += ntloadf(&part[(size_t)c * B * NQKV + (size_t)b * NQKV + 5120 + j]);
    nvrow[(size_t)b * KVH * HD + j] = v;
  }
}

// ---- flash chunk kernel: K stream + scores -> LDS -> chunk-local softmax
// ---- (3 barriers) -> V stream (2 rows/iter, prefetched through stats) + PV.
// NT loads (read-once), cacheable stores (match fill-path write efficiency).
__global__ void __launch_bounds__(256)
k_flashKV(const float* __restrict__ pastk, const float* __restrict__ pastv,
          const float* __restrict__ nkrow, const float* __restrict__ nvrow,
          const float* __restrict__ qr, const int* __restrict__ steps,
          float* __restrict__ newk, float* __restrict__ newv,
          float* __restrict__ part, float* __restrict__ stats) {
  int ch = blockIdx.x, kvh = blockIdx.y, b = blockIdx.z;
  int t = threadIdx.x;
  __shared__ float sbuf[CROWS][4];   // [row][head] scores -> probs
  __shared__ float redmx[4][4];      // [wave][head] max partials
  __shared__ float redsm[4][4];      // [wave][head] sum partials
  __shared__ float4 red4[4][4][32];  // [wave][head][d4]
  int s0 = ch * CROWS;
  int step = steps[b];
  int L = step + 1;
  int h0 = kvh * 4;
  bool any = (s0 < L);  // block-uniform
  int w = t >> 6;
  int d4 = t & 31, rr = t >> 5;  // V-phase / staging layout

  const float4* srcv = (const float4*)(pastv + ((size_t)(b * KVH + kvh) * S + s0) * HD);
  float4*       dstv = (float4*)(newv + ((size_t)(b * KVH + kvh) * S + s0) * HD);
  float4 vsub = ((const float4*)(nvrow + (size_t)(b * KVH + kvh) * HD))[d4];

  // ================= K phase: barrier-free stream, 16-lane row groups
  {
    int ln = t & 15, rg = t >> 4;
    const float4* qbase = (const float4*)(qr + ((size_t)b * H + h0) * HD);
    float4 q0[4], q1[4];
#pragma unroll
    for (int h = 0; h < 4; h++) {
      q0[h] = qbase[h * 32 + ln];
      q1[h] = qbase[h * 32 + ln + 16];
    }
    const float4* subp = (const float4*)(nkrow + (size_t)(b * KVH + kvh) * HD);
    float4 sub0 = subp[ln], sub1 = subp[ln + 16];
    const float4* src = (const float4*)(pastk + ((size_t)(b * KVH + kvh) * S + s0) * HD);
    float4*       dst = (float4*)(newk + ((size_t)(b * KVH + kvh) * S + s0) * HD);
#pragma unroll 4
    for (int it = 0; it < CROWS / 16; ++it) {
      int row = it * 16 + rg;
      size_t o0 = (size_t)row * 32 + ln;
      float4 k0 = ntload4(&src[o0]);
      float4 k1 = ntload4(&src[o0 + 16]);
      if (s0 + row == step) { k0 = sub0; k1 = sub1; }
      dst[o0] = k0;
      dst[o0 + 16] = k1;
      if (s0 + it * 16 < L) {  // wave-uniform skip of dead 16-row groups
        float a0, a1, a2, a3;
        a0 = fmaf(k0.x, q0[0].x, fmaf(k0.y, q0[0].y, fmaf(k0.z, q0[0].z, fmaf(k0.w, q0[0].w,
             fmaf(k1.x, q1[0].x, fmaf(k1.y, q1[0].y, fmaf(k1.z, q1[0].z, k1.w * q1[0].w)))))));
        a1 = fmaf(k0.x, q0[1].x, fmaf(k0.y, q0[1].y, fmaf(k0.z, q0[1].z, fmaf(k0.w, q0[1].w,
             fmaf(k1.x, q1[1].x, fmaf(k1.y, q1[1].y, fmaf(k1.z, q1[1].z, k1.w * q1[1].w)))))));
        a2 = fmaf(k0.x, q0[2].x, fmaf(k0.y, q0[2].y, fmaf(k0.z, q0[2].z, fmaf(k0.w, q0[2].w,
             fmaf(k1.x, q1[2].x, fmaf(k1.y, q1[2].y, fmaf(k1.z, q1[2].z, k1.w * q1[2].w)))))));
        a3 = fmaf(k0.x, q0[3].x, fmaf(k0.y, q0[3].y, fmaf(k0.z, q0[3].z, fmaf(k0.w, q0[3].w,
             fmaf(k1.x, q1[3].x, fmaf(k1.y, q1[3].y, fmaf(k1.z, q1[3].z, k1.w * q1[3].w)))))));
#pragma unroll
        for (int o = 1; o < 16; o <<= 1) {
          a0 += __shfl_xor(a0, o);
          a1 += __shfl_xor(a1, o);
          a2 += __shfl_xor(a2, o);
          a3 += __shfl_xor(a3, o);
        }
        if (ln < 4) {
          float my = (ln == 0) ? a0 : (ln == 1) ? a1 : (ln == 2) ? a2 : a3;
          sbuf[row][ln] = my * SCALE;
        }
      }
    }
  }
  // prefetch first V row-pair: loads stay in flight across the stats barriers
  float4 pv0 = ntload4(&srcv[(size_t)rr * 32 + d4]);
  float4 pv1 = ntload4(&srcv[(size_t)(rr + 8) * 32 + d4]);
  __syncthreads();  // A: sbuf complete

  // ================= chunk-local softmax stats (m, l), sbuf -> p, 3 barriers
  bool valid = any && (s0 + t < L);
  float s_0 = valid ? sbuf[t][0] : -1e30f;
  float s_1 = valid ? sbuf[t][1] : -1e30f;
  float s_2 = valid ? sbuf[t][2] : -1e30f;
  float s_3 = valid ? sbuf[t][3] : -1e30f;
  float mx0 = s_0, mx1 = s_1, mx2 = s_2, mx3 = s_3;
#pragma unroll
  for (int o = 1; o < 64; o <<= 1) {
    mx0 = fmaxf(mx0, __shfl_xor(mx0, o));
    mx1 = fmaxf(mx1, __shfl_xor(mx1, o));
    mx2 = fmaxf(mx2, __shfl_xor(mx2, o));
    mx3 = fmaxf(mx3, __shfl_xor(mx3, o));
  }
  if ((t & 63) == 0) { redmx[w][0] = mx0; redmx[w][1] = mx1; redmx[w][2] = mx2; redmx[w][3] = mx3; }
  __syncthreads();  // B: wave maxes ready
  float m0 = fmaxf(fmaxf(redmx[0][0], redmx[1][0]), fmaxf(redmx[2][0], redmx[3][0]));
  float m1 = fmaxf(fmaxf(redmx[0][1], redmx[1][1]), fmaxf(redmx[2][1], redmx[3][1]));
  float m2 = fmaxf(fmaxf(redmx[0][2], redmx[1][2]), fmaxf(redmx[2][2], redmx[3][2]));
  float m3 = fmaxf(fmaxf(redmx[0][3], redmx[1][3]), fmaxf(redmx[2][3], redmx[3][3]));
  float e0 = valid ? __expf(s_0 - m0) : 0.f;
  float e1 = valid ? __expf(s_1 - m1) : 0.f;
  float e2 = valid ? __expf(s_2 - m2) : 0.f;
  float e3 = valid ? __expf(s_3 - m3) : 0.f;
  float es0 = e0, es1 = e1, es2 = e2, es3 = e3;
#pragma unroll
  for (int o = 1; o < 64; o <<= 1) {
    es0 += __shfl_xor(es0, o);
    es1 += __shfl_xor(es1, o);
    es2 += __shfl_xor(es2, o);
    es3 += __shfl_xor(es3, o);
  }
  if ((t & 63) == 0) { redsm[w][0] = es0; redsm[w][1] = es1; redsm[w][2] = es2; redsm[w][3] = es3; }
  sbuf[t][0] = e0; sbuf[t][1] = e1; sbuf[t][2] = e2; sbuf[t][3] = e3;  // own row only
  __syncthreads();  // C: probs + wave sums ready
  float l0 = redsm[0][0] + redsm[1][0] + redsm[2][0] + redsm[3][0];
  float l1 = redsm[0][1] + redsm[1][1] + redsm[2][1] + redsm[3][1];
  float l2 = redsm[0][2] + redsm[1][2] + redsm[2][2] + redsm[3][2];
  float l3 = redsm[0][3] + redsm[1][3] + redsm[2][3] + redsm[3][3];

  // ================= V phase: barrier-free stream, 2 rows/iter, prefetched
  float4 a0 = make_float4(0.f, 0.f, 0.f, 0.f), a1 = a0, a2 = a0, a3 = a0;
#pragma unroll 2
  for (int i = 0; i < CROWS / 16; ++i) {
    int r0 = i * 16 + rr, r1 = r0 + 8;
    float4 v0 = pv0, v1 = pv1;
    if (i + 1 < CROWS / 16) {
      pv0 = ntload4(&srcv[(size_t)(r0 + 16) * 32 + d4]);
      pv1 = ntload4(&srcv[(size_t)(r1 + 16) * 32 + d4]);
    }
    if (s0 + r0 == step) v0 = vsub;
    if (s0 + r1 == step) v1 = vsub;
    dstv[(size_t)r0 * 32 + d4] = v0;
    dstv[(size_t)r1 * 32 + d4] = v1;
    if (any && i * 16 < L - s0) {  // block-uniform; probs zero-padded
      float p00 = sbuf[r0][0], p01 = sbuf[r0][1], p02 = sbuf[r0][2], p03 = sbuf[r0][3];
      float p10 = sbuf[r1][0], p11 = sbuf[r1][1], p12 = sbuf[r1][2], p13 = sbuf[r1][3];
      a0.x = fmaf(p00, v0.x, fmaf(p10, v1.x, a0.x));
      a0.y = fmaf(p00, v0.y, fmaf(p10, v1.y, a0.y));
      a0.z = fmaf(p00, v0.z, fmaf(p10, v1.z, a0.z));
      a0.w = fmaf(p00, v0.w, fmaf(p10, v1.w, a0.w));
      a1.x = fmaf(p01, v0.x, fmaf(p11, v1.x, a1.x));
      a1.y = fmaf(p01, v0.y, fmaf(p11, v1.y, a1.y));
      a1.z = fmaf(p01, v0.z, fmaf(p11, v1.z, a1.z));
      a1.w = fmaf(p01, v0.w, fmaf(p11, v1.w, a1.w));
      a2.x = fmaf(p02, v0.x, fmaf(p12, v1.x, a2.x));
      a2.y = fmaf(p02, v0.y, fmaf(p12, v1.y, a2.y));
      a2.z = fmaf(p02, v0.z, fmaf(p12, v1.z, a2.z));
      a2.w = fmaf(p02, v0.w, fmaf(p12, v1.w, a2.w));
      a3.x = fmaf(p03, v0.x, fmaf(p13, v1.x, a3.x));
      a3.y = fmaf(p03, v0.y, fmaf(p13, v1.y, a3.y));
      a3.z = fmaf(p03, v0.z, fmaf(p13, v1.z, a3.z));
      a3.w = fmaf(p03, v0.w, fmaf(p13, v1.w, a3.w));
    }
  }
  // combine rr pairs within wave (t^32 flips rr bit 0)
  a0.x += __shfl_xor(a0.x, 32); a0.y += __shfl_xor(a0.y, 32);
  a0.z += __shfl_xor(a0.z, 32); a0.w += __shfl_xor(a0.w, 32);
  a1.x += __shfl_xor(a1.x, 32); a1.y += __shfl_xor(a1.y, 32);
  a1.z += __shfl_xor(a1.z, 32); a1.w += __shfl_xor(a1.w, 32);
  a2.x += __shfl_xor(a2.x, 32); a2.y += __shfl_xor(a2.y, 32);
  a2.z += __shfl_xor(a2.z, 32); a2.w += __shfl_xor(a2.w, 32);
  a3.x += __shfl_xor(a3.x, 32); a3.y += __shfl_xor(a3.y, 32);
  a3.z += __shfl_xor(a3.z, 32); a3.w += __shfl_xor(a3.w, 32);
  if ((t & 32) == 0) {
    red4[w][0][d4] = a0; red4[w][1][d4] = a1; red4[w][2][d4] = a2; red4[w][3][d4] = a3;
  }
  __syncthreads();  // D: partials ready
  if (t < 128) {
    int hh = t >> 5, dd = t & 31;
    float4 x0 = red4[0][hh][dd], x1 = red4[1][hh][dd], x2 = red4[2][hh][dd], x3 = red4[3][hh][dd];
    float4 s;
    s.x = (x0.x + x1.x) + (x2.x + x3.x);
    s.y = (x0.y + x1.y) + (x2.y + x3.y);
    s.z = (x0.z + x1.z) + (x2.z + x3.z);
    s.w = (x0.w + x1.w) + (x2.w + x3.w);
    ((float4*)(part + (((size_t)ch * B + b) * KVH + kvh) * 512))[t] = s;
  }
  if (t == 0) {
    size_t si = (((size_t)ch * B + b) * KVH + kvh) * 8;
    stats[si + 0] = m0; stats[si + 1] = l0;
    stats[si + 2] = m1; stats[si + 3] = l1;
    stats[si + 4] = m2; stats[si + 5] = l2;
    stats[si + 6] = m3; stats[si + 7] = l3;
  }
}

// ------------- split-S merge: ctx = sum(e^{m-M} acc) / sum(e^{m-M} l)
__global__ void k_reduce_ctx(const float* __restrict__ part, const float* __restrict__ stats,
                             float* __restrict__ ctx) {
  int i = blockIdx.x * 256 + threadIdx.x;  // < B*D
  int b = i >> 12, r = i & 4095, h = r >> 7, d = r & 127;
  int kvh = h >> 2, hl = h & 3;
  float M = -1e30f;
#pragma unroll
  for (int c = 0; c < NCH; c++)
    M = fmaxf(M, stats[(((size_t)c * B + b) * KVH + kvh) * 8 + hl * 2]);
  float num = 0.f, den = 0.f;
#pragma unroll
  for (int c = 0; c < NCH; c++) {
    size_t si = (((size_t)c * B + b) * KVH + kvh) * 8 + hl * 2;
    float wgt = __expf(stats[si] - M);
    den += wgt * stats[si + 1];
    num += wgt * ntloadf(&part[(((size_t)c * B + b) * KVH + kvh) * 512 + hl * 128 + d]);
  }
  ctx[i] = num / den;
}

// ----------------------------------------------- output projection (M=16)
// Same LDS-transposed-activation treatment as k_proj.
__global__ void k_wo(const float* __restrict__ ctx, const float* __restrict__ Wo,
                     float* __restrict__ part) {
  __shared__ float4 cxT[D / WSPLIT][4];  // [k][b4] : 8 KB
  int t = threadIdx.x;
  int n = blockIdx.x * 256 + t;  // < 4096
  int k0 = blockIdx.y * (D / WSPLIT);
#pragma unroll
  for (int i = 0; i < (D / WSPLIT) * 4 / 256; i++) {
    int idx = i * 256 + t;
    int k = idx >> 2, b4 = idx & 3;
    cxT[k][b4] = make_float4(ctx[(size_t)(b4 * 4 + 0) * D + k0 + k],
                             ctx[(size_t)(b4 * 4 + 1) * D + k0 + k],
                             ctx[(size_t)(b4 * 4 + 2) * D + k0 + k],
                             ctx[(size_t)(b4 * 4 + 3) * D + k0 + k]);
  }
  float acc[B];
#pragma unroll
  for (int b = 0; b < B; b++) acc[b] = 0.f;
  const float* wp = Wo + (size_t)k0 * D + n;
  __syncthreads();
#pragma unroll 4
  for (int k = 0; k < D / WSPLIT; k++) {
    float wv = ntloadf(&wp[(size_t)k * D]);  // Wo read exactly once
    float4 h0 = cxT[k][0], h1 = cxT[k][1], h2 = cxT[k][2], h3 = cxT[k][3];
    acc[0]  = fmaf(h0.x, wv, acc[0]);  acc[1]  = fmaf(h0.y, wv, acc[1]);
    acc[2]  = fmaf(h0.z, wv, acc[2]);  acc[3]  = fmaf(h0.w, wv, acc[3]);
    acc[4]  = fmaf(h1.x, wv, acc[4]);  acc[5]  = fmaf(h1.y, wv, acc[5]);
    acc[6]  = fmaf(h1.z, wv, acc[6]);  acc[7]  = fmaf(h1.w, wv, acc[7]);
    acc[8]  = fmaf(h2.x, wv, acc[8]);  acc[9]  = fmaf(h2.y, wv, acc[9]);
    acc[10] = fmaf(h2.z, wv, acc[10]); acc[11] = fmaf(h2.w, wv, acc[11]);
    acc[12] = fmaf(h3.x, wv, acc[12]); acc[13] = fmaf(h3.y, wv, acc[13]);
    acc[14] = fmaf(h3.z, wv, acc[14]); acc[15] = fmaf(h3.w, wv, acc[15]);
  }
  float* p = part + (size_t)blockIdx.y * (B * D);
#pragma unroll
  for (int b = 0; b < B; b++) p[(size_t)b * D + n] = acc[b];  // cacheable
}

__global__ void k_reduce_out(const float* __restrict__ part, float* __restrict__ out) {
  int i = blockIdx.x * 256 + threadIdx.x;  // < B*D
  float s = 0.f;
#pragma unroll
  for (int c = 0; c < WSPLIT; c++) s += ntloadf(&part[(size_t)c * B * D + i]);
  out[i] = s;
}

// ----------------------------------------------------------------- launch
extern "C" void kernel_launch(void* const* d_in, const int* in_sizes, int n_in,
                              void* d_out, int out_size, void* d_ws, size_t ws_size,
                              hipStream_t stream) {
  const float* hs    = (const float*)d_in[0];
  const int*   steps = (const int*)d_in[2];
  const float* cosb  = (const float*)d_in[3];
  const float* sinb  = (const float*)d_in[4];
  const float* pk    = (const float*)d_in[5];
  const float* pvv   = (const float*)d_in[6];
  const float* Wq    = (const float*)d_in[7];
  const float* Wk    = (const float*)d_in[8];
  const float* Wv    = (const float*)d_in[9];
  const float* Wo    = (const float*)d_in[10];

  float* attn_out = (float*)d_out;
  float* newk = attn_out + (size_t)B * D;
  float* newv = newk + (size_t)B * KVH * S * HD;

  float* ws = (float*)d_ws;
  // Region A (lifetimes disjoint): proj partials (3.1M) -> Wo partials (2.1M)
  float* A        = ws;                               // 3,145,728 floats
  float* p_part   = A;
  float* p_wopart = A;
  float* p_pvpart = A + 3145728;                      // 1,048,576
  float* p_stats  = p_pvpart + 1048576;               //    16,384
  float* p_qr     = p_stats + 16384;                  //    65,536
  float* p_nkrow  = p_qr + (size_t)B * D;             //    16,384
  float* p_nvrow  = p_nkrow + (size_t)B * KVH * HD;   //    16,384
  float* p_ctx    = p_nvrow + (size_t)B * KVH * HD;   //    65,536

  hipLaunchKernelGGL(k_proj, dim3(NQKV / 256, PSPLIT), dim3(256), 0, stream,
                     hs, Wq, Wk, Wv, p_part);
  hipLaunchKernelGGL(k_reduce_rope, dim3(B * 3584 / 256), dim3(256), 0, stream,
                     p_part, cosb, sinb, steps, p_qr, p_nkrow, p_nvrow);
  hipLaunchKernelGGL(k_flashKV, dim3(NCH, KVH, B), dim3(256), 0, stream,
                     pk, pvv, p_nkrow, p_nvrow, p_qr, steps, newk, newv,
                     p_pvpart, p_stats);
  hipLaunchKernelGGL(k_reduce_ctx, dim3(B * D / 256), dim3(256), 0, stream,
                     p_pvpart, p_stats, p_ctx);
  hipLaunchKernelGGL(k_wo, dim3(D / 256, WSPLIT), dim3(256), 0, stream,
                     p_ctx, Wo, p_wopart);
  hipLaunchKernelGGL(k_reduce_out, dim3(B * D / 256), dim3(256), 0, stream,
                     p_wopart, attn_out);
}